// Round 4
// baseline (12302.447 us; speedup 1.0000x reference)
//
#include <hip/hip_runtime.h>
#include <hip/hip_bf16.h>
#include <math.h>

#define N_ROWS 131072
#define DIN    768
#define DHID   512
#define DCODE  256
#define KCODES 512

typedef short short8 __attribute__((ext_vector_type(8)));
typedef float f32x4  __attribute__((ext_vector_type(4)));
typedef unsigned int   u32;
typedef unsigned short u16;

__device__ __forceinline__ void gload16(const void* g, void* l) {
    __builtin_amdgcn_global_load_lds(
        (const __attribute__((address_space(1))) u32*)g,
        (__attribute__((address_space(3))) u32*)l, 16, 0, 0);
}

__device__ __forceinline__ u16 f2bf(float f) {
    u32 u = __builtin_bit_cast(u32, f);
    return (u16)((u + 0x7fffu + ((u >> 16) & 1u)) >> 16);
}

// bijective XCD-chunk swizzle (nwg % 8 == 0 for all our grids)
__device__ __forceinline__ void xcd_swizzle(int& bxs, int& bys) {
    const int GX  = gridDim.x;
    const int nwg = GX * gridDim.y;
    const int lid = blockIdx.y * GX + blockIdx.x;
    const int chunk = nwg >> 3;
    const int nlid  = (lid & 7) * chunk + (lid >> 3);
    bxs = nlid % GX;
    bys = nlid / GX;
}

// ---------------------------------------------------------------------------
// fp32 tiled SGEMM — BITWISE path (h1, z, dots). Each C element is one fp32
// fmaf chain over k ascending from 0; bias added as separate rounded add.
// Reg-prefetch + LDS double-buffer: 1 barrier per K-step, global latency
// hidden under compute. ARGMIN: skip C write; per-block per-row lex-min of
// dist = cnorm - 2*dot over the block's 128 cols -> partial (dist,idx).
// ---------------------------------------------------------------------------
template<bool RELU, bool ARGMIN>
__global__ __launch_bounds__(256, 2)
void gemm_kernel(const float* __restrict__ A, const float* __restrict__ B,
                 const float* __restrict__ bias, float* __restrict__ C,
                 const float* __restrict__ cnorm,
                 float* __restrict__ pdist, int* __restrict__ pidx,
                 int M, int N, int K)
{
    __shared__ float As[2][16][132];
    __shared__ float Bs[2][16][132];
    const int t = threadIdx.x;
    int bxs, bys;
    xcd_swizzle(bxs, bys);
    const int bm = bys * 128, bn = bxs * 128;
    const int tx = t & 15, ty = t >> 4;

    float acc[8][8];
    #pragma unroll
    for (int i = 0; i < 8; i++)
        #pragma unroll
        for (int j = 0; j < 8; j++) acc[i][j] = 0.f;

    const int ar = t >> 2;          // 0..63
    const int ac = (t & 3) * 4;     // 0,4,8,12
    const float* Arow0 = A + (size_t)(bm + ar) * K + ac;
    const float* Arow1 = A + (size_t)(bm + ar + 64) * K + ac;
    const int br = t >> 4;
    const int bc = (t & 15) * 8;
    const float* Brow = B + (size_t)br * N + bn + bc;

    // prologue: stage tile 0 into LDS[0]
    float4 sa0 = *(const float4*)(Arow0);
    float4 sa1 = *(const float4*)(Arow1);
    float4 sb0 = *(const float4*)(Brow);
    float4 sb1 = *(const float4*)(Brow + 4);
    As[0][ac+0][ar] = sa0.x; As[0][ac+1][ar] = sa0.y; As[0][ac+2][ar] = sa0.z; As[0][ac+3][ar] = sa0.w;
    As[0][ac+0][ar+64] = sa1.x; As[0][ac+1][ar+64] = sa1.y; As[0][ac+2][ar+64] = sa1.z; As[0][ac+3][ar+64] = sa1.w;
    *(float4*)&Bs[0][br][bc]     = sb0;
    *(float4*)&Bs[0][br][bc + 4] = sb1;

    const int NT = K >> 4;
    int cur = 0;
    for (int tt = 0; tt < NT; tt++) {
        __syncthreads();            // LDS[cur] writes visible; prev-buf readers done
        if (tt + 1 < NT) {          // prefetch next tile into regs (lands during compute)
            const int k0 = (tt + 1) << 4;
            sa0 = *(const float4*)(Arow0 + k0);
            sa1 = *(const float4*)(Arow1 + k0);
            sb0 = *(const float4*)(Brow + (size_t)k0 * N);
            sb1 = *(const float4*)(Brow + (size_t)k0 * N + 4);
        }
        #pragma unroll
        for (int kk = 0; kk < 16; kk++) {
            float4 A0 = *(const float4*)&As[cur][kk][ty * 8];
            float4 A1 = *(const float4*)&As[cur][kk][ty * 8 + 4];
            float4 B0 = *(const float4*)&Bs[cur][kk][tx * 4];
            float4 B1 = *(const float4*)&Bs[cur][kk][tx * 4 + 64];
            float av[8] = {A0.x,A0.y,A0.z,A0.w,A1.x,A1.y,A1.z,A1.w};
            float bv[8] = {B0.x,B0.y,B0.z,B0.w,B1.x,B1.y,B1.z,B1.w};
            #pragma unroll
            for (int i = 0; i < 8; i++)
                #pragma unroll
                for (int j = 0; j < 8; j++)
                    acc[i][j] = fmaf(av[i], bv[j], acc[i][j]);
        }
        if (tt + 1 < NT) {
            const int nb = cur ^ 1;
            As[nb][ac+0][ar] = sa0.x; As[nb][ac+1][ar] = sa0.y; As[nb][ac+2][ar] = sa0.z; As[nb][ac+3][ar] = sa0.w;
            As[nb][ac+0][ar+64] = sa1.x; As[nb][ac+1][ar+64] = sa1.y; As[nb][ac+2][ar+64] = sa1.z; As[nb][ac+3][ar+64] = sa1.w;
            *(float4*)&Bs[nb][br][bc]     = sb0;
            *(float4*)&Bs[nb][br][bc + 4] = sb1;
        }
        cur ^= 1;
    }

    if (ARGMIN) {
        // cols owned: bn+tx*4+j (acc[.][j]) and bn+64+tx*4+j (acc[.][4+j])
        float cn0[4], cn1[4];
        #pragma unroll
        for (int j = 0; j < 4; j++) {
            cn0[j] = cnorm[bn + tx * 4 + j];
            cn1[j] = cnorm[bn + 64 + tx * 4 + j];
        }
        #pragma unroll
        for (int i = 0; i < 8; i++) {
            float d1 = INFINITY;
            int   i1 = 0x7fffffff;
            #pragma unroll
            for (int j = 0; j < 4; j++) {
                int   c = bn + tx * 4 + j;
                float d = __fsub_rn(cn0[j], __fmul_rn(2.0f, acc[i][j]));
                if (d < d1 || (d == d1 && c < i1)) { d1 = d; i1 = c; }
            }
            #pragma unroll
            for (int j = 0; j < 4; j++) {
                int   c = bn + 64 + tx * 4 + j;
                float d = __fsub_rn(cn1[j], __fmul_rn(2.0f, acc[i][4 + j]));
                if (d < d1 || (d == d1 && c < i1)) { d1 = d; i1 = c; }
            }
            // reduce across the 16 tx-lanes of this ty-group (lex-min)
            #pragma unroll
            for (int m = 1; m < 16; m <<= 1) {
                float od = __shfl_xor(d1, m);
                int   oi = __shfl_xor(i1, m);
                if (od < d1 || (od == d1 && oi < i1)) { d1 = od; i1 = oi; }
            }
            if (tx == 0) {
                size_t r = (size_t)bxs * M + (bm + ty * 8 + i);
                pdist[r] = d1;
                pidx[r]  = i1;
            }
        }
        return;
    }

    const int crow = bm + ty * 8;
    const int c0   = bn + tx * 4;
    float bs0[4], bs1[4];
    if (bias) {
        float4 bb0 = *(const float4*)(bias + c0);
        float4 bb1 = *(const float4*)(bias + c0 + 64);
        bs0[0]=bb0.x; bs0[1]=bb0.y; bs0[2]=bb0.z; bs0[3]=bb0.w;
        bs1[0]=bb1.x; bs1[1]=bb1.y; bs1[2]=bb1.z; bs1[3]=bb1.w;
    } else {
        bs0[0]=bs0[1]=bs0[2]=bs0[3]=0.f;
        bs1[0]=bs1[1]=bs1[2]=bs1[3]=0.f;
    }
    #pragma unroll
    for (int i = 0; i < 8; i++) {
        float4 o0, o1;
        float v;
        v = __fadd_rn(acc[i][0], bs0[0]); o0.x = RELU ? fmaxf(v, 0.f) : v;
        v = __fadd_rn(acc[i][1], bs0[1]); o0.y = RELU ? fmaxf(v, 0.f) : v;
        v = __fadd_rn(acc[i][2], bs0[2]); o0.z = RELU ? fmaxf(v, 0.f) : v;
        v = __fadd_rn(acc[i][3], bs0[3]); o0.w = RELU ? fmaxf(v, 0.f) : v;
        v = __fadd_rn(acc[i][4], bs1[0]); o1.x = RELU ? fmaxf(v, 0.f) : v;
        v = __fadd_rn(acc[i][5], bs1[1]); o1.y = RELU ? fmaxf(v, 0.f) : v;
        v = __fadd_rn(acc[i][6], bs1[2]); o1.z = RELU ? fmaxf(v, 0.f) : v;
        v = __fadd_rn(acc[i][7], bs1[3]); o1.w = RELU ? fmaxf(v, 0.f) : v;
        *(float4*)&C[(size_t)(crow + i) * N + c0]      = o0;
        *(float4*)&C[(size_t)(crow + i) * N + c0 + 64] = o1;
    }
}

// ---------------------------------------------------------------------------
// bf16 MFMA GEMM (decoder; lenient tolerance). Unchanged from round 3 except
// XCD swizzle. C = act(A[M,K] @ BT[N,K]^T + bias), A/BT bf16 row-major.
// ---------------------------------------------------------------------------
template<bool RELU, bool GATHER, bool OUT_BF16>
__global__ __launch_bounds__(256, 2)
void mfma_gemm(const u16* __restrict__ A, const u16* __restrict__ BT,
               const float* __restrict__ bias, const int* __restrict__ rowidx,
               void* __restrict__ Cout, int M, int N, int K)
{
    __shared__ char lds[65536];
    const int t    = threadIdx.x;
    const int lane = t & 63, wid = t >> 6;
    const int wm   = wid >> 1, wn = wid & 1;
    int bxs, bys;
    xcd_swizzle(bxs, bys);
    const int bm = bys * 128, bn = bxs * 128;

    const int sr = lane >> 3;
    const int sc = ((lane & 7) ^ sr) * 8;
    const u16* aptr[4];
    const u16* bptr[4];
    #pragma unroll
    for (int c = 0; c < 4; c++) {
        int gc   = wid * 4 + c;
        int arow = bm + 8 * gc + sr;
        if (GATHER) arow = rowidx[arow];
        aptr[c] = A  + (size_t)arow * K + sc;
        int brow = bn + 8 * gc + sr;
        bptr[c] = BT + (size_t)brow * K + sc;
    }

    f32x4 acc[4][4];
    #pragma unroll
    for (int i = 0; i < 4; i++)
        #pragma unroll
        for (int j = 0; j < 4; j++) acc[i][j] = (f32x4)0.f;

    const int koff0 = (16 * (lane >> 4))      ^ ((lane & 7) << 4);
    const int koff1 = (64 + 16 * (lane >> 4)) ^ ((lane & 7) << 4);
    const int arow_rd = wm * 64 + (lane & 15);
    const int brow_rd = wn * 64 + (lane & 15);

    const int NT = K >> 6;
    #pragma unroll
    for (int c = 0; c < 4; c++) {
        int gc = wid * 4 + c;
        gload16(aptr[c], lds + gc * 1024);
        gload16(bptr[c], lds + 16384 + gc * 1024);
    }
    __syncthreads();

    int cur = 0;
    for (int tt = 0; tt < NT; tt++) {
        if (tt + 1 < NT) {
            const int k0 = (tt + 1) << 6;
            char* nb = lds + (cur ^ 1) * 32768;
            #pragma unroll
            for (int c = 0; c < 4; c++) {
                int gc = wid * 4 + c;
                gload16(aptr[c] + k0, nb + gc * 1024);
                gload16(bptr[c] + k0, nb + 16384 + gc * 1024);
            }
        }
        char* ldsA = lds + cur * 32768;
        char* ldsB = ldsA + 16384;
        #pragma unroll
        for (int kk = 0; kk < 2; kk++) {
            const int ko = kk ? koff1 : koff0;
            short8 af[4], bfr[4];
            #pragma unroll
            for (int i = 0; i < 4; i++)
                af[i]  = *(const short8*)(ldsA + (arow_rd + i * 16) * 128 + ko);
            #pragma unroll
            for (int j = 0; j < 4; j++)
                bfr[j] = *(const short8*)(ldsB + (brow_rd + j * 16) * 128 + ko);
            #pragma unroll
            for (int i = 0; i < 4; i++)
                #pragma unroll
                for (int j = 0; j < 4; j++)
                    acc[i][j] = __builtin_amdgcn_mfma_f32_16x16x32_bf16(
                        af[i], bfr[j], acc[i][j], 0, 0, 0);
        }
        __syncthreads();
        cur ^= 1;
    }

    const int er = (lane >> 4) * 4;
    const int ec = lane & 15;
    #pragma unroll
    for (int j = 0; j < 4; j++) {
        int col  = bn + wn * 64 + j * 16 + ec;
        float bb = bias[col];
        #pragma unroll
        for (int i = 0; i < 4; i++) {
            #pragma unroll
            for (int e = 0; e < 4; e++) {
                int r   = bm + wm * 64 + i * 16 + er + e;
                float v = acc[i][j][e] + bb;
                if (RELU) v = fmaxf(v, 0.f);
                if (OUT_BF16) ((u16*)Cout)[(size_t)r * N + col]  = f2bf(v);
                else          ((float*)Cout)[(size_t)r * N + col] = v;
            }
        }
    }
}

// ---------------------------------------------------------------------------
__global__ void transpose_cb_kernel(const float* __restrict__ cb, float* __restrict__ cbT)
{
    int tid = blockIdx.x * 256 + threadIdx.x;
    int k = tid >> 8;
    int d = tid & 255;
    cbT[(size_t)d * KCODES + k] = cb[(size_t)k * DCODE + d];
}

__global__ void cast_bf16_kernel(const float* __restrict__ in, u16* __restrict__ out, int n)
{
    int i = blockIdx.x * 256 + threadIdx.x;
    if (i < n) out[i] = f2bf(in[i]);
}

__global__ void castT_bf16_kernel(const float* __restrict__ in, u16* __restrict__ out,
                                  int K, int N)
{
    int i = blockIdx.x * 256 + threadIdx.x;
    if (i >= K * N) return;
    int n = i / K, k = i - n * K;
    out[i] = f2bf(in[(size_t)k * N + n]);
}

// ---------------------------------------------------------------------------
// ||c_k||^2 replicating numpy float32 pairwise-summation bitwise.
// ---------------------------------------------------------------------------
__global__ void cnorm_np_kernel(const float* __restrict__ cb, float* __restrict__ cnorm)
{
    int k = blockIdx.x * 64 + threadIdx.x;
    if (k >= KCODES) return;
    const float* c = cb + (size_t)k * DCODE;
    float bsum[2];
    #pragma unroll
    for (int b = 0; b < 2; b++) {
        const float* a = c + b * 128;
        float r[8];
        #pragma unroll
        for (int j = 0; j < 8; j++) r[j] = __fmul_rn(a[j], a[j]);
        for (int i = 8; i < 128; i += 8)
            #pragma unroll
            for (int j = 0; j < 8; j++)
                r[j] = __fadd_rn(r[j], __fmul_rn(a[i + j], a[i + j]));
        bsum[b] = __fadd_rn(
            __fadd_rn(__fadd_rn(r[0], r[1]), __fadd_rn(r[2], r[3])),
            __fadd_rn(__fadd_rn(r[4], r[5]), __fadd_rn(r[6], r[7])));
    }
    cnorm[k] = __fadd_rn(bsum[0], bsum[1]);
}

// ---------------------------------------------------------------------------
// ||z_r||^2 (lenient; feeds loss only). One wave per row.
// ---------------------------------------------------------------------------
__global__ void znorm_kernel(const float* __restrict__ z, float* __restrict__ znorm)
{
    int gw   = (blockIdx.x * blockDim.x + threadIdx.x) >> 6;
    int lane = threadIdx.x & 63;
    const float* zr = z + (size_t)gw * DCODE;
    float4 v = *(const float4*)(zr + lane * 4);
    float s = v.x*v.x + v.y*v.y + v.z*v.z + v.w*v.w;
    for (int off = 32; off; off >>= 1) s += __shfl_xor(s, off);
    if (lane == 0) znorm[gw] = s;
}

// ---------------------------------------------------------------------------
// Final argmin: lex-min over the 4 per-colblock partials; rowloss = ||z||^2+d.
// ---------------------------------------------------------------------------
__global__ void final_argmin_kernel(const float* __restrict__ pdist,
                                    const int* __restrict__ pidx,
                                    const float* __restrict__ znorm,
                                    float* __restrict__ idx_f,
                                    int* __restrict__ idx_i,
                                    float* __restrict__ rowloss)
{
    int r = blockIdx.x * 256 + threadIdx.x;
    if (r >= N_ROWS) return;
    float d = pdist[r];
    int   i = pidx[r];
    #pragma unroll
    for (int b = 1; b < 4; b++) {
        float od = pdist[(size_t)b * N_ROWS + r];
        int   oi = pidx[(size_t)b * N_ROWS + r];
        if (od < d || (od == d && oi < i)) { d = od; i = oi; }
    }
    idx_f[r]   = (float)i;
    idx_i[r]   = i;
    rowloss[r] = znorm[r] + d;
}

// ---------------------------------------------------------------------------
__global__ void loss_reduce_kernel(const float* __restrict__ rowloss,
                                   double* __restrict__ acc, int n)
{
    double s = 0.0;
    for (int i = blockIdx.x * blockDim.x + threadIdx.x; i < n; i += gridDim.x * blockDim.x)
        s += (double)rowloss[i];
    for (int off = 32; off; off >>= 1) s += __shfl_xor(s, off);
    __shared__ double red[4];
    int lane = threadIdx.x & 63, wave = threadIdx.x >> 6;
    if (lane == 0) red[wave] = s;
    __syncthreads();
    if (threadIdx.x == 0) {
        double b = red[0] + red[1] + red[2] + red[3];
        atomicAdd(acc, b);
    }
}

__global__ void finalize_kernel(const double* __restrict__ acc, float* __restrict__ out)
{
    out[0] = (float)(acc[0] / ((double)N_ROWS * (double)DCODE));
}

// ---------------------------------------------------------------------------
extern "C" void kernel_launch(void* const* d_in, const int* in_sizes, int n_in,
                              void* d_out, int out_size, void* d_ws, size_t ws_size,
                              hipStream_t stream)
{
    const float* x  = (const float*)d_in[0];
    const float* W1 = (const float*)d_in[1];
    const float* b1 = (const float*)d_in[2];
    const float* W2 = (const float*)d_in[3];
    const float* b2 = (const float*)d_in[4];
    const float* cb = (const float*)d_in[5];
    const float* W3 = (const float*)d_in[6];
    const float* b3 = (const float*)d_in[7];
    const float* W4 = (const float*)d_in[8];
    const float* b4 = (const float*)d_in[9];
    float* out = (float*)d_out;
    char*  ws  = (char*)d_ws;

    float*  buf0    = (float*) (ws);                      // 256 MB: h1 (dead after z)
    float*  pdist   = (float*) (ws);                      // alias ex-h1: 2 MB
    int*    pidx    = (int*)   (ws + 2097152);            // 2 MB
    float*  znorm   = (float*) (ws + 4194304);            // 512 KB
    float*  zbuf    = (float*) (ws + 268435456);          // 128 MB: z
    u16*    h2b     = (u16*)   (ws + 268435456);          // alias: h2 bf16 (z dead)
    float*  cbT     = (float*) (ws + 402653184);          // 512 KB
    float*  cnorm   = (float*) (ws + 403177472);          // 2 KB
    int*    idxi    = (int*)   (ws + 403181568);          // 512 KB
    float*  rowloss = (float*) (ws + 403705856);          // 512 KB
    double* lossa   = (double*)(ws + 404230144);          // 8 B
    u16*    cbB     = (u16*)   (ws + 404230208);          // 256 KB
    u16*    W3T     = (u16*)   (ws + 404492352);          // 256 KB
    u16*    W4T     = (u16*)   (ws + 404754496);          // 768 KB

    float* idxf    = out + (size_t)N_ROWS * DIN;
    float* lossout = idxf + N_ROWS;

    hipMemsetAsync(ws + 404230144, 0, 8, stream);

    transpose_cb_kernel<<<512, 256, 0, stream>>>(cb, cbT);
    cnorm_np_kernel<<<8, 64, 0, stream>>>(cb, cnorm);
    cast_bf16_kernel<<<(KCODES*DCODE)/256, 256, 0, stream>>>(cb, cbB, KCODES*DCODE);
    castT_bf16_kernel<<<(DCODE*DHID)/256, 256, 0, stream>>>(W3, W3T, DCODE, DHID);
    castT_bf16_kernel<<<(DHID*DIN)/256, 256, 0, stream>>>(W4, W4T, DHID, DIN);

    // encoder (bitwise fp32 chains)
    gemm_kernel<true,  false><<<dim3(DHID/128,  N_ROWS/128), 256, 0, stream>>>(
        x, W1, b1, buf0, nullptr, nullptr, nullptr, N_ROWS, DHID, DIN);        // h1
    gemm_kernel<false, false><<<dim3(DCODE/128, N_ROWS/128), 256, 0, stream>>>(
        buf0, W2, b2, zbuf, nullptr, nullptr, nullptr, N_ROWS, DCODE, DHID);   // z
    znorm_kernel<<<N_ROWS/4, 256, 0, stream>>>(zbuf, znorm);
    // dots + fused argmin (no dots materialization; partials into ex-h1)
    gemm_kernel<false, true ><<<dim3(KCODES/128, N_ROWS/128), 256, 0, stream>>>(
        zbuf, cbT, nullptr, nullptr, cnorm, pdist, pidx, N_ROWS, KCODES, DCODE);
    final_argmin_kernel<<<N_ROWS/256, 256, 0, stream>>>(
        pdist, pidx, znorm, idxf, idxi, rowloss);

    // decoder (bf16 MFMA)
    mfma_gemm<true,  true,  true ><<<dim3(DHID/128, N_ROWS/128), 256, 0, stream>>>(
        cbB, W3T, b3, idxi, (void*)h2b, N_ROWS, DHID, DCODE);                  // h2
    mfma_gemm<false, false, false><<<dim3(DIN/128,  N_ROWS/128), 256, 0, stream>>>(
        h2b, W4T, b4, nullptr, (void*)out, N_ROWS, DIN, DHID);                 // recon

    loss_reduce_kernel<<<256, 256, 0, stream>>>(rowloss, lossa, N_ROWS);
    finalize_kernel<<<1, 1, 0, stream>>>(lossa, lossout);
}

// Round 5
// 2166.278 us; speedup vs baseline: 5.6791x; 5.6791x over previous
//
#include <hip/hip_runtime.h>
#include <hip/hip_bf16.h>
#include <math.h>

#define N_ROWS 131072
#define DIN    768
#define DHID   512
#define DCODE  256
#define KCODES 512

typedef short short8 __attribute__((ext_vector_type(8)));
typedef float f32x4  __attribute__((ext_vector_type(4)));
typedef unsigned int   u32;
typedef unsigned short u16;

__device__ __forceinline__ void gload16(const void* g, void* l) {
    __builtin_amdgcn_global_load_lds(
        (const __attribute__((address_space(1))) u32*)g,
        (__attribute__((address_space(3))) u32*)l, 16, 0, 0);
}

__device__ __forceinline__ u16 f2bf(float f) {
    u32 u = __builtin_bit_cast(u32, f);
    return (u16)((u + 0x7fffu + ((u >> 16) & 1u)) >> 16);
}

// m157-form XCD swizzle: tile_id = (hw_lid % 8) * chunk + hw_lid / 8.
// XCD k (hw lids ≡ k mod 8) processes a CONTIGUOUS tile chunk -> col-blocks
// sharing an A row-panel land in the same XCD's L2. Requires nwg % 8 == 0.
__device__ __forceinline__ void xcd_swizzle(int& bxs, int& bys) {
    const int GX  = gridDim.x;
    const int nwg = GX * gridDim.y;
    const int lid = blockIdx.y * GX + blockIdx.x;
    const int chunk = nwg >> 3;
    const int nlid  = (lid & 7) * chunk + (lid >> 3);
    bxs = nlid % GX;
    bys = nlid / GX;
}

// ---------------------------------------------------------------------------
// fp32 tiled SGEMM — BITWISE path (h1, z, dots). Round-3 single-buffer loop
// (52 VGPR, no spill). Each C element: one fp32 fmaf chain over k ascending
// from 0; bias as separate rounded add. LDS stride 132 (bank-conflict pad).
// ARGMIN: skip C write; per-block per-row lex-min of dist = cnorm - 2*dot
// over the block's 128 cols -> partial (dist,idx) per (colblock,row).
// ---------------------------------------------------------------------------
template<bool RELU, bool ARGMIN>
__global__ __launch_bounds__(256, 2)
void gemm_kernel(const float* __restrict__ A, const float* __restrict__ B,
                 const float* __restrict__ bias, float* __restrict__ C,
                 const float* __restrict__ cnorm,
                 float* __restrict__ pdist, int* __restrict__ pidx,
                 int M, int N, int K)
{
    __shared__ float As[16][132];
    __shared__ float Bs[16][132];
    const int t = threadIdx.x;
    int bxs, bys;
    xcd_swizzle(bxs, bys);
    const int bm = bys * 128, bn = bxs * 128;
    const int tx = t & 15, ty = t >> 4;

    float acc[8][8];
    #pragma unroll
    for (int i = 0; i < 8; i++)
        #pragma unroll
        for (int j = 0; j < 8; j++) acc[i][j] = 0.f;

    const int ar = t >> 2;          // 0..63
    const int ac = (t & 3) * 4;     // 0,4,8,12
    const float* Arow0 = A + (size_t)(bm + ar) * K + ac;
    const float* Arow1 = A + (size_t)(bm + ar + 64) * K + ac;
    const int br = t >> 4;
    const int bc = (t & 15) * 8;
    const float* Brow = B + (size_t)br * N + bn + bc;

    for (int k0 = 0; k0 < K; k0 += 16) {
        float4 a0 = *(const float4*)(Arow0 + k0);
        float4 a1 = *(const float4*)(Arow1 + k0);
        float4 b0 = *(const float4*)(Brow + (size_t)k0 * N);
        float4 b1 = *(const float4*)(Brow + (size_t)k0 * N + 4);
        __syncthreads();
        As[ac+0][ar] = a0.x; As[ac+1][ar] = a0.y; As[ac+2][ar] = a0.z; As[ac+3][ar] = a0.w;
        As[ac+0][ar+64] = a1.x; As[ac+1][ar+64] = a1.y; As[ac+2][ar+64] = a1.z; As[ac+3][ar+64] = a1.w;
        *(float4*)&Bs[br][bc]     = b0;
        *(float4*)&Bs[br][bc + 4] = b1;
        __syncthreads();
        #pragma unroll
        for (int kk = 0; kk < 16; kk++) {
            float4 A0 = *(const float4*)&As[kk][ty * 8];
            float4 A1 = *(const float4*)&As[kk][ty * 8 + 4];
            float4 B0 = *(const float4*)&Bs[kk][tx * 4];
            float4 B1 = *(const float4*)&Bs[kk][tx * 4 + 64];
            float av[8] = {A0.x,A0.y,A0.z,A0.w,A1.x,A1.y,A1.z,A1.w};
            float bv[8] = {B0.x,B0.y,B0.z,B0.w,B1.x,B1.y,B1.z,B1.w};
            #pragma unroll
            for (int i = 0; i < 8; i++)
                #pragma unroll
                for (int j = 0; j < 8; j++)
                    acc[i][j] = fmaf(av[i], bv[j], acc[i][j]);
        }
    }

    if (ARGMIN) {
        float cn0[4], cn1[4];
        #pragma unroll
        for (int j = 0; j < 4; j++) {
            cn0[j] = cnorm[bn + tx * 4 + j];
            cn1[j] = cnorm[bn + 64 + tx * 4 + j];
        }
        #pragma unroll
        for (int i = 0; i < 8; i++) {
            float d1 = INFINITY;
            int   i1 = 0x7fffffff;
            #pragma unroll
            for (int j = 0; j < 4; j++) {
                int   c = bn + tx * 4 + j;
                float d = __fsub_rn(cn0[j], __fmul_rn(2.0f, acc[i][j]));
                if (d < d1 || (d == d1 && c < i1)) { d1 = d; i1 = c; }
            }
            #pragma unroll
            for (int j = 0; j < 4; j++) {
                int   c = bn + 64 + tx * 4 + j;
                float d = __fsub_rn(cn1[j], __fmul_rn(2.0f, acc[i][4 + j]));
                if (d < d1 || (d == d1 && c < i1)) { d1 = d; i1 = c; }
            }
            #pragma unroll
            for (int m = 1; m < 16; m <<= 1) {
                float od = __shfl_xor(d1, m);
                int   oi = __shfl_xor(i1, m);
                if (od < d1 || (od == d1 && oi < i1)) { d1 = od; i1 = oi; }
            }
            if (tx == 0) {
                size_t r = (size_t)bxs * M + (bm + ty * 8 + i);
                pdist[r] = d1;
                pidx[r]  = i1;
            }
        }
        return;
    }

    const int crow = bm + ty * 8;
    const int c0   = bn + tx * 4;
    float bs0[4], bs1[4];
    if (bias) {
        float4 bb0 = *(const float4*)(bias + c0);
        float4 bb1 = *(const float4*)(bias + c0 + 64);
        bs0[0]=bb0.x; bs0[1]=bb0.y; bs0[2]=bb0.z; bs0[3]=bb0.w;
        bs1[0]=bb1.x; bs1[1]=bb1.y; bs1[2]=bb1.z; bs1[3]=bb1.w;
    } else {
        bs0[0]=bs0[1]=bs0[2]=bs0[3]=0.f;
        bs1[0]=bs1[1]=bs1[2]=bs1[3]=0.f;
    }
    #pragma unroll
    for (int i = 0; i < 8; i++) {
        float4 o0, o1;
        float v;
        v = __fadd_rn(acc[i][0], bs0[0]); o0.x = RELU ? fmaxf(v, 0.f) : v;
        v = __fadd_rn(acc[i][1], bs0[1]); o0.y = RELU ? fmaxf(v, 0.f) : v;
        v = __fadd_rn(acc[i][2], bs0[2]); o0.z = RELU ? fmaxf(v, 0.f) : v;
        v = __fadd_rn(acc[i][3], bs0[3]); o0.w = RELU ? fmaxf(v, 0.f) : v;
        v = __fadd_rn(acc[i][4], bs1[0]); o1.x = RELU ? fmaxf(v, 0.f) : v;
        v = __fadd_rn(acc[i][5], bs1[1]); o1.y = RELU ? fmaxf(v, 0.f) : v;
        v = __fadd_rn(acc[i][6], bs1[2]); o1.z = RELU ? fmaxf(v, 0.f) : v;
        v = __fadd_rn(acc[i][7], bs1[3]); o1.w = RELU ? fmaxf(v, 0.f) : v;
        *(float4*)&C[(size_t)(crow + i) * N + c0]      = o0;
        *(float4*)&C[(size_t)(crow + i) * N + c0 + 64] = o1;
    }
}

// ---------------------------------------------------------------------------
// bf16 MFMA GEMM (decoder; lenient tolerance). Round-3 structure + swizzle.
// ---------------------------------------------------------------------------
template<bool RELU, bool GATHER, bool OUT_BF16>
__global__ __launch_bounds__(256, 2)
void mfma_gemm(const u16* __restrict__ A, const u16* __restrict__ BT,
               const float* __restrict__ bias, const int* __restrict__ rowidx,
               void* __restrict__ Cout, int M, int N, int K)
{
    __shared__ char lds[65536];
    const int t    = threadIdx.x;
    const int lane = t & 63, wid = t >> 6;
    const int wm   = wid >> 1, wn = wid & 1;
    int bxs, bys;
    xcd_swizzle(bxs, bys);
    const int bm = bys * 128, bn = bxs * 128;

    const int sr = lane >> 3;
    const int sc = ((lane & 7) ^ sr) * 8;
    const u16* aptr[4];
    const u16* bptr[4];
    #pragma unroll
    for (int c = 0; c < 4; c++) {
        int gc   = wid * 4 + c;
        int arow = bm + 8 * gc + sr;
        if (GATHER) arow = rowidx[arow];
        aptr[c] = A  + (size_t)arow * K + sc;
        int brow = bn + 8 * gc + sr;
        bptr[c] = BT + (size_t)brow * K + sc;
    }

    f32x4 acc[4][4];
    #pragma unroll
    for (int i = 0; i < 4; i++)
        #pragma unroll
        for (int j = 0; j < 4; j++) acc[i][j] = (f32x4)0.f;

    const int koff0 = (16 * (lane >> 4))      ^ ((lane & 7) << 4);
    const int koff1 = (64 + 16 * (lane >> 4)) ^ ((lane & 7) << 4);
    const int arow_rd = wm * 64 + (lane & 15);
    const int brow_rd = wn * 64 + (lane & 15);

    const int NT = K >> 6;
    #pragma unroll
    for (int c = 0; c < 4; c++) {
        int gc = wid * 4 + c;
        gload16(aptr[c], lds + gc * 1024);
        gload16(bptr[c], lds + 16384 + gc * 1024);
    }
    __syncthreads();

    int cur = 0;
    for (int tt = 0; tt < NT; tt++) {
        if (tt + 1 < NT) {
            const int k0 = (tt + 1) << 6;
            char* nb = lds + (cur ^ 1) * 32768;
            #pragma unroll
            for (int c = 0; c < 4; c++) {
                int gc = wid * 4 + c;
                gload16(aptr[c] + k0, nb + gc * 1024);
                gload16(bptr[c] + k0, nb + 16384 + gc * 1024);
            }
        }
        char* ldsA = lds + cur * 32768;
        char* ldsB = ldsA + 16384;
        #pragma unroll
        for (int kk = 0; kk < 2; kk++) {
            const int ko = kk ? koff1 : koff0;
            short8 af[4], bfr[4];
            #pragma unroll
            for (int i = 0; i < 4; i++)
                af[i]  = *(const short8*)(ldsA + (arow_rd + i * 16) * 128 + ko);
            #pragma unroll
            for (int j = 0; j < 4; j++)
                bfr[j] = *(const short8*)(ldsB + (brow_rd + j * 16) * 128 + ko);
            #pragma unroll
            for (int i = 0; i < 4; i++)
                #pragma unroll
                for (int j = 0; j < 4; j++)
                    acc[i][j] = __builtin_amdgcn_mfma_f32_16x16x32_bf16(
                        af[i], bfr[j], acc[i][j], 0, 0, 0);
        }
        __syncthreads();
        cur ^= 1;
    }

    const int er = (lane >> 4) * 4;
    const int ec = lane & 15;
    #pragma unroll
    for (int j = 0; j < 4; j++) {
        int col  = bn + wn * 64 + j * 16 + ec;
        float bb = bias[col];
        #pragma unroll
        for (int i = 0; i < 4; i++) {
            #pragma unroll
            for (int e = 0; e < 4; e++) {
                int r   = bm + wm * 64 + i * 16 + er + e;
                float v = acc[i][j][e] + bb;
                if (RELU) v = fmaxf(v, 0.f);
                if (OUT_BF16) ((u16*)Cout)[(size_t)r * N + col]  = f2bf(v);
                else          ((float*)Cout)[(size_t)r * N + col] = v;
            }
        }
    }
}

// ---------------------------------------------------------------------------
__global__ void transpose_cb_kernel(const float* __restrict__ cb, float* __restrict__ cbT)
{
    int tid = blockIdx.x * 256 + threadIdx.x;
    int k = tid >> 8;
    int d = tid & 255;
    cbT[(size_t)d * KCODES + k] = cb[(size_t)k * DCODE + d];
}

__global__ void cast_bf16_kernel(const float* __restrict__ in, u16* __restrict__ out, int n)
{
    int i = blockIdx.x * 256 + threadIdx.x;
    if (i < n) out[i] = f2bf(in[i]);
}

__global__ void castT_bf16_kernel(const float* __restrict__ in, u16* __restrict__ out,
                                  int K, int N)
{
    int i = blockIdx.x * 256 + threadIdx.x;
    if (i >= K * N) return;
    int n = i / K, k = i - n * K;
    out[i] = f2bf(in[(size_t)k * N + n]);
}

// ---------------------------------------------------------------------------
// ||c_k||^2 replicating numpy float32 pairwise-summation bitwise.
// ---------------------------------------------------------------------------
__global__ void cnorm_np_kernel(const float* __restrict__ cb, float* __restrict__ cnorm)
{
    int k = blockIdx.x * 64 + threadIdx.x;
    if (k >= KCODES) return;
    const float* c = cb + (size_t)k * DCODE;
    float bsum[2];
    #pragma unroll
    for (int b = 0; b < 2; b++) {
        const float* a = c + b * 128;
        float r[8];
        #pragma unroll
        for (int j = 0; j < 8; j++) r[j] = __fmul_rn(a[j], a[j]);
        for (int i = 8; i < 128; i += 8)
            #pragma unroll
            for (int j = 0; j < 8; j++)
                r[j] = __fadd_rn(r[j], __fmul_rn(a[i + j], a[i + j]));
        bsum[b] = __fadd_rn(
            __fadd_rn(__fadd_rn(r[0], r[1]), __fadd_rn(r[2], r[3])),
            __fadd_rn(__fadd_rn(r[4], r[5]), __fadd_rn(r[6], r[7])));
    }
    cnorm[k] = __fadd_rn(bsum[0], bsum[1]);
}

// ---------------------------------------------------------------------------
__global__ void znorm_kernel(const float* __restrict__ z, float* __restrict__ znorm)
{
    int gw   = (blockIdx.x * blockDim.x + threadIdx.x) >> 6;
    int lane = threadIdx.x & 63;
    const float* zr = z + (size_t)gw * DCODE;
    float4 v = *(const float4*)(zr + lane * 4);
    float s = v.x*v.x + v.y*v.y + v.z*v.z + v.w*v.w;
    for (int off = 32; off; off >>= 1) s += __shfl_xor(s, off);
    if (lane == 0) znorm[gw] = s;
}

// ---------------------------------------------------------------------------
__global__ void final_argmin_kernel(const float* __restrict__ pdist,
                                    const int* __restrict__ pidx,
                                    const float* __restrict__ znorm,
                                    float* __restrict__ idx_f,
                                    int* __restrict__ idx_i,
                                    float* __restrict__ rowloss)
{
    int r = blockIdx.x * 256 + threadIdx.x;
    if (r >= N_ROWS) return;
    float d = pdist[r];
    int   i = pidx[r];
    #pragma unroll
    for (int b = 1; b < 4; b++) {
        float od = pdist[(size_t)b * N_ROWS + r];
        int   oi = pidx[(size_t)b * N_ROWS + r];
        if (od < d || (od == d && oi < i)) { d = od; i = oi; }
    }
    idx_f[r]   = (float)i;
    idx_i[r]   = i;
    rowloss[r] = znorm[r] + d;
}

// ---------------------------------------------------------------------------
__global__ void loss_reduce_kernel(const float* __restrict__ rowloss,
                                   double* __restrict__ acc, int n)
{
    double s = 0.0;
    for (int i = blockIdx.x * blockDim.x + threadIdx.x; i < n; i += gridDim.x * blockDim.x)
        s += (double)rowloss[i];
    for (int off = 32; off; off >>= 1) s += __shfl_xor(s, off);
    __shared__ double red[4];
    int lane = threadIdx.x & 63, wave = threadIdx.x >> 6;
    if (lane == 0) red[wave] = s;
    __syncthreads();
    if (threadIdx.x == 0) {
        double b = red[0] + red[1] + red[2] + red[3];
        atomicAdd(acc, b);
    }
}

__global__ void finalize_kernel(const double* __restrict__ acc, float* __restrict__ out)
{
    out[0] = (float)(acc[0] / ((double)N_ROWS * (double)DCODE));
}

// ---------------------------------------------------------------------------
extern "C" void kernel_launch(void* const* d_in, const int* in_sizes, int n_in,
                              void* d_out, int out_size, void* d_ws, size_t ws_size,
                              hipStream_t stream)
{
    const float* x  = (const float*)d_in[0];
    const float* W1 = (const float*)d_in[1];
    const float* b1 = (const float*)d_in[2];
    const float* W2 = (const float*)d_in[3];
    const float* b2 = (const float*)d_in[4];
    const float* cb = (const float*)d_in[5];
    const float* W3 = (const float*)d_in[6];
    const float* b3 = (const float*)d_in[7];
    const float* W4 = (const float*)d_in[8];
    const float* b4 = (const float*)d_in[9];
    float* out = (float*)d_out;
    char*  ws  = (char*)d_ws;

    float*  buf0    = (float*) (ws);                      // 256 MB: h1 (dead after z)
    float*  pdist   = (float*) (ws);                      // alias ex-h1: 2 MB
    int*    pidx    = (int*)   (ws + 2097152);            // 2 MB
    float*  znorm   = (float*) (ws + 4194304);            // 512 KB
    float*  zbuf    = (float*) (ws + 268435456);          // 128 MB: z
    u16*    h2b     = (u16*)   (ws + 268435456);          // alias: h2 bf16 (z dead)
    float*  cbT     = (float*) (ws + 402653184);          // 512 KB
    float*  cnorm   = (float*) (ws + 403177472);          // 2 KB
    int*    idxi    = (int*)   (ws + 403181568);          // 512 KB
    float*  rowloss = (float*) (ws + 403705856);          // 512 KB
    double* lossa   = (double*)(ws + 404230144);          // 8 B
    u16*    cbB     = (u16*)   (ws + 404230208);          // 256 KB
    u16*    W3T     = (u16*)   (ws + 404492352);          // 256 KB
    u16*    W4T     = (u16*)   (ws + 404754496);          // 768 KB

    float* idxf    = out + (size_t)N_ROWS * DIN;
    float* lossout = idxf + N_ROWS;

    hipMemsetAsync(ws + 404230144, 0, 8, stream);

    transpose_cb_kernel<<<512, 256, 0, stream>>>(cb, cbT);
    cnorm_np_kernel<<<8, 64, 0, stream>>>(cb, cnorm);
    cast_bf16_kernel<<<(KCODES*DCODE)/256, 256, 0, stream>>>(cb, cbB, KCODES*DCODE);
    castT_bf16_kernel<<<(DCODE*DHID)/256, 256, 0, stream>>>(W3, W3T, DCODE, DHID);
    castT_bf16_kernel<<<(DHID*DIN)/256, 256, 0, stream>>>(W4, W4T, DHID, DIN);

    // encoder (bitwise fp32 chains; round-3 proven loop)
    gemm_kernel<true,  false><<<dim3(DHID/128,  N_ROWS/128), 256, 0, stream>>>(
        x, W1, b1, buf0, nullptr, nullptr, nullptr, N_ROWS, DHID, DIN);        // h1
    gemm_kernel<false, false><<<dim3(DCODE/128, N_ROWS/128), 256, 0, stream>>>(
        buf0, W2, b2, zbuf, nullptr, nullptr, nullptr, N_ROWS, DCODE, DHID);   // z
    znorm_kernel<<<N_ROWS/4, 256, 0, stream>>>(zbuf, znorm);
    // dots + fused argmin (no dots materialization)
    gemm_kernel<false, true ><<<dim3(KCODES/128, N_ROWS/128), 256, 0, stream>>>(
        zbuf, cbT, nullptr, nullptr, cnorm, pdist, pidx, N_ROWS, KCODES, DCODE);
    final_argmin_kernel<<<N_ROWS/256, 256, 0, stream>>>(
        pdist, pidx, znorm, idxf, idxi, rowloss);

    // decoder (bf16 MFMA)
    mfma_gemm<true,  true,  true ><<<dim3(DHID/128, N_ROWS/128), 256, 0, stream>>>(
        cbB, W3T, b3, idxi, (void*)h2b, N_ROWS, DHID, DCODE);                  // h2
    mfma_gemm<false, false, false><<<dim3(DIN/128,  N_ROWS/128), 256, 0, stream>>>(
        h2b, W4T, b4, nullptr, (void*)out, N_ROWS, DIN, DHID);                 // recon

    loss_reduce_kernel<<<256, 256, 0, stream>>>(rowloss, lossa, N_ROWS);
    finalize_kernel<<<1, 1, 0, stream>>>(lossa, lossout);
}

// Round 6
// 1170.912 us; speedup vs baseline: 10.5067x; 1.8501x over previous
//
#include <hip/hip_runtime.h>
#include <hip/hip_bf16.h>
#include <math.h>

#define N_ROWS 131072
#define DIN    768
#define DHID   512
#define DCODE  256
#define KC     512
#define TAU    5e-3f

typedef short short8 __attribute__((ext_vector_type(8)));
typedef float f32x4  __attribute__((ext_vector_type(4)));
typedef unsigned int   u32;
typedef unsigned short u16;

__device__ __forceinline__ void gload16(const void* g, void* l) {
    __builtin_amdgcn_global_load_lds(
        (const __attribute__((address_space(1))) u32*)g,
        (__attribute__((address_space(3))) u32*)l, 16, 0, 0);
}

__device__ __forceinline__ u16 f2bf(float f) {
    u32 u = __builtin_bit_cast(u32, f);
    return (u16)((u + 0x7fffu + ((u >> 16) & 1u)) >> 16);
}
__device__ __forceinline__ float bf2f(u16 h) {
    u32 u = ((u32)h) << 16;
    return __builtin_bit_cast(float, u);
}

// m157-form bijective XCD swizzle (all grids have nwg % 8 == 0)
__device__ __forceinline__ void xcd_swizzle(int& bxs, int& bys) {
    const int GX  = gridDim.x;
    const int nwg = GX * gridDim.y;
    const int lid = blockIdx.y * GX + blockIdx.x;
    const int chunk = nwg >> 3;
    const int nlid  = (lid & 7) * chunk + (lid >> 3);
    bxs = nlid % GX;
    bys = nlid / GX;
}

// hi/lo bf16 split of a float4, written to two 8B LDS slots
__device__ __forceinline__ void split_write(char* hidst, char* lodst, float4 v) {
    u16 h0 = f2bf(v.x), h1 = f2bf(v.y), h2 = f2bf(v.z), h3 = f2bf(v.w);
    u16 l0 = f2bf(__fsub_rn(v.x, bf2f(h0)));
    u16 l1 = f2bf(__fsub_rn(v.y, bf2f(h1)));
    u16 l2 = f2bf(__fsub_rn(v.z, bf2f(h2)));
    u16 l3 = f2bf(__fsub_rn(v.w, bf2f(h3)));
    ushort4 hi; hi.x = h0; hi.y = h1; hi.z = h2; hi.w = h3;
    ushort4 lo; lo.x = l0; lo.y = l1; lo.z = l2; lo.w = l3;
    *(ushort4*)hidst = hi;
    *(ushort4*)lodst = lo;
}

// ---------------------------------------------------------------------------
// Split-2 bf16 MFMA GEMM, 128x128 tile, BK=32, 4 waves (2x2), dbuf LDS.
// C = A@B^T(+bias) with A = Ahi+Alo, B = Bhi+Blo; 3 MFMA per fragment pair
// (hi*hi + hi*lo + lo*hi). LDS rows are 128B = [hi 4 slots | lo 4 slots],
// XOR-swizzled by (row&7) over the 8 slots (conflict-free ds_read_b128).
// EPI=0 (H1): A = f32 (split on the fly via reg-stage), epilogue relu+bias,
//             writes hi/lo bf16 pair.
// EPI=1 (DOTS): A = bf16 pair; epilogue dist = cnorm - 2*(acc+bc), per-row
//             top-2 lex-min over the block's 128 cols -> strip partials.
// ---------------------------------------------------------------------------
template<int EPI>
__global__ __launch_bounds__(256, 2)
void split2_gemm(const float* __restrict__ Af32,
                 const u16* __restrict__ Ahi, const u16* __restrict__ Alo,
                 const u16* __restrict__ Bhi, const u16* __restrict__ Blo,
                 const float* __restrict__ bias,
                 const float* __restrict__ cnorm,
                 u16* __restrict__ Chi, u16* __restrict__ Clo,
                 float* __restrict__ pd1, int* __restrict__ pi1,
                 float* __restrict__ pd2,
                 int M, int N, int K)
{
    __shared__ char lds[65536];   // buf b: A-pair @ b*32768 (16K), B-pair @ +16384
    const int t = threadIdx.x, lane = t & 63, wid = t >> 6;
    const int wm = wid >> 1, wn = wid & 1;
    int bxs, bys; xcd_swizzle(bxs, bys);
    const int bm = bys * 128, bn = bxs * 128;

    // staging: 16 chunks/array-pair of 1KB (8 rows x 128B); lane: row sr, slot q
    const int sr = lane >> 3, qq = lane & 7, sl = qq ^ sr;   // sl = logical slot
    const u16* bsrc[4];
    #pragma unroll
    for (int c = 0; c < 4; c++) {
        int row = bn + (wid * 4 + c) * 8 + sr;
        const u16* base = (sl < 4) ? Bhi : Blo;
        bsrc[c] = base + (size_t)row * K + (sl & 3) * 8;
    }
    const u16* asrc[4];
    const float* a32src[4];
    int adhi[4], adlo[4];
    if constexpr (EPI == 1) {
        #pragma unroll
        for (int c = 0; c < 4; c++) {
            int row = bm + (wid * 4 + c) * 8 + sr;
            const u16* base = (sl < 4) ? Ahi : Alo;
            asrc[c] = base + (size_t)row * K + (sl & 3) * 8;
        }
    } else {
        #pragma unroll
        for (int c = 0; c < 4; c++) {
            int id = c * 256 + t;
            int row = id >> 3, k4 = id & 7;       // k4: float4 index within 32-k slice
            a32src[c] = Af32 + (size_t)(bm + row) * K + k4 * 4;
            int s = k4 >> 1, hf = k4 & 1;
            adhi[c] = row * 128 + ((s ^ (row & 7)) << 4) + hf * 8;
            adlo[c] = row * 128 + (((s | 4) ^ (row & 7)) << 4) + hf * 8;
        }
    }

    f32x4 acc[4][4];
    #pragma unroll
    for (int i = 0; i < 4; i++)
        #pragma unroll
        for (int j = 0; j < 4; j++) acc[i][j] = (f32x4)0.f;

    const int fr = lane & 15, sw = lane & 7;
    const int offhi = (((lane >> 4) ^ sw) << 4);
    const int offlo = ((((lane >> 4) | 4) ^ sw) << 4);
    const int arow = wm * 64 + fr, brow = wn * 64 + fr;
    const int NT = K >> 5;

    // prologue: stage tile 0 into buf0
    {
        char* ab  = lds;
        char* bb2 = lds + 16384;
        #pragma unroll
        for (int c = 0; c < 4; c++)
            gload16(bsrc[c], bb2 + (wid * 4 + c) * 1024);
        if constexpr (EPI == 1) {
            #pragma unroll
            for (int c = 0; c < 4; c++)
                gload16(asrc[c], ab + (wid * 4 + c) * 1024);
        } else {
            #pragma unroll
            for (int c = 0; c < 4; c++) {
                float4 v = *(const float4*)(a32src[c]);
                split_write(ab + adhi[c], ab + adlo[c], v);
            }
        }
    }
    __syncthreads();

    int cur = 0;
    for (int tt = 0; tt < NT; tt++) {
        const bool pf = (tt + 1 < NT);
        char* nb = lds + ((cur ^ 1) * 32768);
        float4 rg[4];
        if (pf) {
            const int kadv = (tt + 1) * 32;
            #pragma unroll
            for (int c = 0; c < 4; c++)
                gload16(bsrc[c] + kadv, nb + 16384 + (wid * 4 + c) * 1024);
            if constexpr (EPI == 1) {
                #pragma unroll
                for (int c = 0; c < 4; c++)
                    gload16(asrc[c] + kadv, nb + (wid * 4 + c) * 1024);
            } else {
                #pragma unroll
                for (int c = 0; c < 4; c++)
                    rg[c] = *(const float4*)(a32src[c] + kadv);
            }
        }
        char* ab  = lds + cur * 32768;
        char* bb2 = ab + 16384;
        short8 ah[4], al[4];
        #pragma unroll
        for (int i = 0; i < 4; i++) {
            ah[i] = *(const short8*)(ab + ((arow + i * 16) << 7) + offhi);
            al[i] = *(const short8*)(ab + ((arow + i * 16) << 7) + offlo);
        }
        #pragma unroll
        for (int j = 0; j < 4; j++) {
            short8 bh = *(const short8*)(bb2 + ((brow + j * 16) << 7) + offhi);
            short8 bl = *(const short8*)(bb2 + ((brow + j * 16) << 7) + offlo);
            #pragma unroll
            for (int i = 0; i < 4; i++) {
                acc[i][j] = __builtin_amdgcn_mfma_f32_16x16x32_bf16(ah[i], bh, acc[i][j], 0, 0, 0);
                acc[i][j] = __builtin_amdgcn_mfma_f32_16x16x32_bf16(al[i], bh, acc[i][j], 0, 0, 0);
                acc[i][j] = __builtin_amdgcn_mfma_f32_16x16x32_bf16(ah[i], bl, acc[i][j], 0, 0, 0);
            }
        }
        if (pf) {
            if constexpr (EPI == 0) {
                #pragma unroll
                for (int c = 0; c < 4; c++)
                    split_write(nb + adhi[c], nb + adlo[c], rg[c]);
            }
        }
        __syncthreads();
        cur ^= 1;
    }

    if constexpr (EPI == 1) {
        const int ec = lane & 15, g = lane >> 4;
        float cnv[4], bcv[4];
        #pragma unroll
        for (int j = 0; j < 4; j++) {
            int c = bn + wn * 64 + j * 16 + ec;
            cnv[j] = cnorm[c]; bcv[j] = bias[c];
        }
        const int strip = bxs * 2 + wn;
        #pragma unroll
        for (int i = 0; i < 4; i++) {
            #pragma unroll
            for (int e = 0; e < 4; e++) {
                float d1 = INFINITY, d2 = INFINITY; int i1 = 0x7fffffff;
                #pragma unroll
                for (int j = 0; j < 4; j++) {
                    int c = bn + wn * 64 + j * 16 + ec;
                    float d = __fsub_rn(cnv[j],
                              __fmul_rn(2.0f, __fadd_rn(acc[i][j][e], bcv[j])));
                    if (d < d1 || (d == d1 && c < i1)) { d2 = d1; d1 = d; i1 = c; }
                    else if (d < d2) d2 = d;
                }
                #pragma unroll
                for (int m = 1; m < 16; m <<= 1) {
                    float od1 = __shfl_xor(d1, m);
                    int   oi1 = __shfl_xor(i1, m);
                    float od2 = __shfl_xor(d2, m);
                    if (od1 < d1 || (od1 == d1 && oi1 < i1)) {
                        d2 = fminf(d1, od2); d1 = od1; i1 = oi1;
                    } else d2 = fminf(d2, od1);
                }
                if (ec == 0) {
                    int r = bm + wm * 64 + i * 16 + g * 4 + e;
                    pd1[(size_t)strip * M + r] = d1;
                    pi1[(size_t)strip * M + r] = i1;
                    pd2[(size_t)strip * M + r] = d2;
                }
            }
        }
        return;
    } else {
        const int er = (lane >> 4) * 4, ec = lane & 15;
        #pragma unroll
        for (int j = 0; j < 4; j++) {
            int col = bn + wn * 64 + j * 16 + ec;
            float bb = bias[col];
            #pragma unroll
            for (int i = 0; i < 4; i++) {
                #pragma unroll
                for (int e = 0; e < 4; e++) {
                    int r = bm + wm * 64 + i * 16 + er + e;
                    float v = fmaxf(__fadd_rn(acc[i][j][e], bb), 0.f);
                    u16 hi = f2bf(v);
                    u16 lo = f2bf(__fsub_rn(v, bf2f(hi)));
                    Chi[(size_t)r * N + col] = hi;
                    Clo[(size_t)r * N + col] = lo;
                }
            }
        }
    }
}

// ---------------------------------------------------------------------------
// Plain bf16 MFMA GEMM (z-for-loss + decoder; lenient tolerance). Round-3/5
// proven structure. C = act(A[M,K] @ BT[N,K]^T + bias).
// ---------------------------------------------------------------------------
template<bool RELU, bool GATHER, bool OUT_BF16>
__global__ __launch_bounds__(256, 2)
void mfma_gemm(const u16* __restrict__ A, const u16* __restrict__ BT,
               const float* __restrict__ bias, const int* __restrict__ rowidx,
               void* __restrict__ Cout, int M, int N, int K)
{
    __shared__ char lds[65536];
    const int t    = threadIdx.x;
    const int lane = t & 63, wid = t >> 6;
    const int wm   = wid >> 1, wn = wid & 1;
    int bxs, bys;
    xcd_swizzle(bxs, bys);
    const int bm = bys * 128, bn = bxs * 128;

    const int sr = lane >> 3;
    const int sc = ((lane & 7) ^ sr) * 8;
    const u16* aptr[4];
    const u16* bptr[4];
    #pragma unroll
    for (int c = 0; c < 4; c++) {
        int gc   = wid * 4 + c;
        int arow = bm + 8 * gc + sr;
        if (GATHER) arow = rowidx[arow];
        aptr[c] = A  + (size_t)arow * K + sc;
        int brow = bn + 8 * gc + sr;
        bptr[c] = BT + (size_t)brow * K + sc;
    }

    f32x4 acc[4][4];
    #pragma unroll
    for (int i = 0; i < 4; i++)
        #pragma unroll
        for (int j = 0; j < 4; j++) acc[i][j] = (f32x4)0.f;

    const int koff0 = (16 * (lane >> 4))      ^ ((lane & 7) << 4);
    const int koff1 = (64 + 16 * (lane >> 4)) ^ ((lane & 7) << 4);
    const int arow_rd = wm * 64 + (lane & 15);
    const int brow_rd = wn * 64 + (lane & 15);

    const int NT = K >> 6;
    #pragma unroll
    for (int c = 0; c < 4; c++) {
        int gc = wid * 4 + c;
        gload16(aptr[c], lds + gc * 1024);
        gload16(bptr[c], lds + 16384 + gc * 1024);
    }
    __syncthreads();

    int cur = 0;
    for (int tt = 0; tt < NT; tt++) {
        if (tt + 1 < NT) {
            const int k0 = (tt + 1) << 6;
            char* nb = lds + (cur ^ 1) * 32768;
            #pragma unroll
            for (int c = 0; c < 4; c++) {
                int gc = wid * 4 + c;
                gload16(aptr[c] + k0, nb + gc * 1024);
                gload16(bptr[c] + k0, nb + 16384 + gc * 1024);
            }
        }
        char* ldsA = lds + cur * 32768;
        char* ldsB = ldsA + 16384;
        #pragma unroll
        for (int kk = 0; kk < 2; kk++) {
            const int ko = kk ? koff1 : koff0;
            short8 af[4], bfr[4];
            #pragma unroll
            for (int i = 0; i < 4; i++)
                af[i]  = *(const short8*)(ldsA + (arow_rd + i * 16) * 128 + ko);
            #pragma unroll
            for (int j = 0; j < 4; j++)
                bfr[j] = *(const short8*)(ldsB + (brow_rd + j * 16) * 128 + ko);
            #pragma unroll
            for (int i = 0; i < 4; i++)
                #pragma unroll
                for (int j = 0; j < 4; j++)
                    acc[i][j] = __builtin_amdgcn_mfma_f32_16x16x32_bf16(
                        af[i], bfr[j], acc[i][j], 0, 0, 0);
        }
        __syncthreads();
        cur ^= 1;
    }

    const int er = (lane >> 4) * 4;
    const int ec = lane & 15;
    #pragma unroll
    for (int j = 0; j < 4; j++) {
        int col  = bn + wn * 64 + j * 16 + ec;
        float bb = bias[col];
        #pragma unroll
        for (int i = 0; i < 4; i++) {
            #pragma unroll
            for (int e = 0; e < 4; e++) {
                int r   = bm + wm * 64 + i * 16 + er + e;
                float v = acc[i][j][e] + bb;
                if (RELU) v = fmaxf(v, 0.f);
                if (OUT_BF16) ((u16*)Cout)[(size_t)r * N + col]  = f2bf(v);
                else          ((float*)Cout)[(size_t)r * N + col] = v;
            }
        }
    }
}

// ---------------------------------------------------------------------------
// Prep kernels
// ---------------------------------------------------------------------------
__global__ void transpose_cb_kernel(const float* __restrict__ cb, float* __restrict__ cbT)
{
    int tid = blockIdx.x * 256 + threadIdx.x;   // 512*256
    int k = tid >> 8;
    int d = tid & 255;
    cbT[(size_t)d * KC + k] = cb[(size_t)k * DCODE + d];
}

__global__ void cast_bf16_kernel(const float* __restrict__ in, u16* __restrict__ out, int n)
{
    int i = blockIdx.x * 256 + threadIdx.x;
    if (i < n) out[i] = f2bf(in[i]);
}

// in [K][N] fp32 -> out [N][K] bf16
__global__ void castT_bf16_kernel(const float* __restrict__ in, u16* __restrict__ out,
                                  int K, int N)
{
    int i = blockIdx.x * 256 + threadIdx.x;
    if (i >= K * N) return;
    int n = i / K, k = i - n * K;
    out[i] = f2bf(in[(size_t)k * N + n]);
}

// W1 [768][512] -> W1T hi/lo [512][768]
__global__ void prep_W1T(const float* __restrict__ W1, u16* __restrict__ Thi,
                         u16* __restrict__ Tlo)
{
    int id = blockIdx.x * 256 + threadIdx.x;    // 512*768
    if (id >= DHID * DIN) return;
    int n = id / DIN, k = id - n * DIN;
    float v = W1[(size_t)k * DHID + n];
    u16 hi = f2bf(v);
    Thi[id] = hi;
    Tlo[id] = f2bf(__fsub_rn(v, bf2f(hi)));
}

// WcT[n][h] = sum_t W2[h][t]*cb[n][t]  (fp64), split to bf16 hi/lo
__global__ void prep_Wc(const float* __restrict__ W2, const float* __restrict__ cb,
                        u16* __restrict__ Thi, u16* __restrict__ Tlo)
{
    int id = blockIdx.x * 256 + threadIdx.x;    // 512*512
    int n = id & 511, h = id >> 9;
    double acc = 0.0;
    for (int tt2 = 0; tt2 < DCODE; tt2++)
        acc += (double)W2[(size_t)h * DCODE + tt2] * (double)cb[(size_t)n * DCODE + tt2];
    float v = (float)acc;
    u16 hi = f2bf(v);
    Thi[(size_t)n * DHID + h] = hi;
    Tlo[(size_t)n * DHID + h] = f2bf(__fsub_rn(v, bf2f(hi)));
}

__global__ void prep_bc(const float* __restrict__ b2, const float* __restrict__ cb,
                        float* __restrict__ bc)
{
    int n = blockIdx.x * 256 + threadIdx.x;
    if (n >= KC) return;
    double acc = 0.0;
    for (int tt2 = 0; tt2 < DCODE; tt2++)
        acc += (double)b2[tt2] * (double)cb[(size_t)n * DCODE + tt2];
    bc[n] = (float)acc;
}

// W2 [512][256] -> W2T bf16 [256][512]
__global__ void prep_W2T(const float* __restrict__ W2, u16* __restrict__ out)
{
    int id = blockIdx.x * 256 + threadIdx.x;    // 256*512
    if (id >= DCODE * DHID) return;
    int t2 = id >> 9, h = id & 511;
    out[id] = f2bf(W2[(size_t)h * DCODE + t2]);
}

// ||c_k||^2 replicating numpy float32 pairwise-summation bitwise (ref-exact).
__global__ void cnorm_np_kernel(const float* __restrict__ cb, float* __restrict__ cnorm)
{
    int k = blockIdx.x * 64 + threadIdx.x;
    if (k >= KC) return;
    const float* c = cb + (size_t)k * DCODE;
    float bsum[2];
    #pragma unroll
    for (int b = 0; b < 2; b++) {
        const float* a = c + b * 128;
        float r[8];
        #pragma unroll
        for (int j = 0; j < 8; j++) r[j] = __fmul_rn(a[j], a[j]);
        for (int i = 8; i < 128; i += 8)
            #pragma unroll
            for (int j = 0; j < 8; j++)
                r[j] = __fadd_rn(r[j], __fmul_rn(a[i + j], a[i + j]));
        bsum[b] = __fadd_rn(
            __fadd_rn(__fadd_rn(r[0], r[1]), __fadd_rn(r[2], r[3])),
            __fadd_rn(__fadd_rn(r[4], r[5]), __fadd_rn(r[6], r[7])));
    }
    cnorm[k] = __fadd_rn(bsum[0], bsum[1]);
}

// ---------------------------------------------------------------------------
// Final merge of 8 strip top-2 partials; flag contested rows (gap < TAU).
// ---------------------------------------------------------------------------
__global__ void final_argmin_flag(const float* __restrict__ pd1,
                                  const int* __restrict__ pi1,
                                  const float* __restrict__ pd2,
                                  const float* __restrict__ znorm,
                                  float* __restrict__ idx_f,
                                  int* __restrict__ idx_i,
                                  float* __restrict__ rowloss,
                                  int* __restrict__ cnt,
                                  int* __restrict__ list)
{
    int r = blockIdx.x * 256 + threadIdx.x;
    if (r >= N_ROWS) return;
    float d1 = pd1[r]; int i1 = pi1[r]; float d2 = pd2[r];
    #pragma unroll
    for (int b = 1; b < 8; b++) {
        float od1 = pd1[(size_t)b * N_ROWS + r];
        int   oi1 = pi1[(size_t)b * N_ROWS + r];
        float od2 = pd2[(size_t)b * N_ROWS + r];
        if (od1 < d1 || (od1 == d1 && oi1 < i1)) {
            d2 = fminf(d1, od2); d1 = od1; i1 = oi1;
        } else d2 = fminf(d2, od1);
    }
    idx_f[r]   = (float)i1;
    idx_i[r]   = i1;
    rowloss[r] = znorm[r] + d1;
    if (d2 - d1 < TAU) {
        int p = atomicAdd(cnt, 1);
        list[p] = r;
    }
}

// ---------------------------------------------------------------------------
// Bitwise fp32 recompute for contested rows: exact k-ascending fmaf chains
// (x -> h1 -> z -> dots -> lex argmin), identical numerics to the validated
// round-2 pipeline. 8 rows per block, 512 threads.
// ---------------------------------------------------------------------------
__global__ __launch_bounds__(512)
void recompute_kernel(const float* __restrict__ x,  const float* __restrict__ W1,
                      const float* __restrict__ b1, const float* __restrict__ W2,
                      const float* __restrict__ b2, const float* __restrict__ cbT,
                      const float* __restrict__ cnorm,
                      const int* __restrict__ cnt,  const int* __restrict__ list,
                      float* __restrict__ idx_f,    int* __restrict__ idx_i)
{
    __shared__ float xs[8][DIN];
    __shared__ float h1s[8][DHID];
    __shared__ float zs[8][DCODE];
    __shared__ float swd[8][8];
    __shared__ int   swi[8][8];
    __shared__ int   rls[8];
    const int t = threadIdx.x;
    const int n = *cnt;

    for (int base = blockIdx.x * 8; base < n; base += gridDim.x * 8) {
        __syncthreads();
        if (t < 8) rls[t] = (base + t < n) ? list[base + t] : -1;
        __syncthreads();
        #pragma unroll
        for (int rr = 0; rr < 8; rr++) {
            int row = rls[rr];
            if (row >= 0)
                for (int i = t; i < DIN; i += 512)
                    xs[rr][i] = x[(size_t)row * DIN + i];
        }
        __syncthreads();
        // h1[t] per row: exact 768-chain
        {
            float acc[8] = {0.f,0.f,0.f,0.f,0.f,0.f,0.f,0.f};
            for (int i = 0; i < DIN; i++) {
                float w = W1[(size_t)i * DHID + t];
                #pragma unroll
                for (int rr = 0; rr < 8; rr++)
                    acc[rr] = fmaf(xs[rr][i], w, acc[rr]);
            }
            float bb = b1[t];
            #pragma unroll
            for (int rr = 0; rr < 8; rr++)
                h1s[rr][t] = fmaxf(__fadd_rn(acc[rr], bb), 0.f);
        }
        __syncthreads();
        // z[t2] for 4 rows per half
        {
            int half = t >> 8, t2 = t & 255;
            float acc[4] = {0.f,0.f,0.f,0.f};
            for (int h = 0; h < DHID; h++) {
                float w = W2[(size_t)h * DCODE + t2];
                #pragma unroll
                for (int q2 = 0; q2 < 4; q2++)
                    acc[q2] = fmaf(h1s[half * 4 + q2][h], w, acc[q2]);
            }
            float bb = b2[t2];
            #pragma unroll
            for (int q2 = 0; q2 < 4; q2++)
                zs[half * 4 + q2][t2] = __fadd_rn(acc[q2], bb);
        }
        __syncthreads();
        // dots[t] + lex argmin
        {
            float acc[8] = {0.f,0.f,0.f,0.f,0.f,0.f,0.f,0.f};
            for (int d = 0; d < DCODE; d++) {
                float c = cbT[(size_t)d * KC + t];
                #pragma unroll
                for (int rr = 0; rr < 8; rr++)
                    acc[rr] = fmaf(zs[rr][d], c, acc[rr]);
            }
            float cn = cnorm[t];
            #pragma unroll
            for (int rr = 0; rr < 8; rr++) {
                float d = __fsub_rn(cn, __fmul_rn(2.0f, acc[rr]));
                int ii = t;
                #pragma unroll
                for (int m = 1; m < 64; m <<= 1) {
                    float od = __shfl_xor(d, m);
                    int   oi = __shfl_xor(ii, m);
                    if (od < d || (od == d && oi < ii)) { d = od; ii = oi; }
                }
                if ((t & 63) == 0) { swd[rr][t >> 6] = d; swi[rr][t >> 6] = ii; }
            }
        }
        __syncthreads();
        if (t < 8) {
            int row = rls[t];
            if (row >= 0) {
                float d = swd[t][0]; int ii = swi[t][0];
                #pragma unroll
                for (int w = 1; w < 8; w++) {
                    float od = swd[t][w]; int oi = swi[t][w];
                    if (od < d || (od == d && oi < ii)) { d = od; ii = oi; }
                }
                idx_i[row] = ii;
                idx_f[row] = (float)ii;
            }
        }
    }
}

// ---------------------------------------------------------------------------
__global__ void znorm_bf16_kernel(const u16* __restrict__ zb, float* __restrict__ znorm)
{
    int gw   = (blockIdx.x * blockDim.x + threadIdx.x) >> 6;
    int lane = threadIdx.x & 63;
    const u16* zr = zb + (size_t)gw * DCODE + lane * 4;
    float s = 0.f;
    #pragma unroll
    for (int e = 0; e < 4; e++) { float v = bf2f(zr[e]); s = fmaf(v, v, s); }
    for (int off = 32; off; off >>= 1) s += __shfl_xor(s, off);
    if (lane == 0) znorm[gw] = s;
}

__global__ void loss_reduce_kernel(const float* __restrict__ rowloss,
                                   double* __restrict__ acc, int n)
{
    double s = 0.0;
    for (int i = blockIdx.x * blockDim.x + threadIdx.x; i < n; i += gridDim.x * blockDim.x)
        s += (double)rowloss[i];
    for (int off = 32; off; off >>= 1) s += __shfl_xor(s, off);
    __shared__ double red[4];
    int lane = threadIdx.x & 63, wave = threadIdx.x >> 6;
    if (lane == 0) red[wave] = s;
    __syncthreads();
    if (threadIdx.x == 0) {
        double b = red[0] + red[1] + red[2] + red[3];
        atomicAdd(acc, b);
    }
}

__global__ void finalize_kernel(const double* __restrict__ acc, float* __restrict__ out)
{
    out[0] = (float)(acc[0] / ((double)N_ROWS * (double)DCODE));
}

// ---------------------------------------------------------------------------
extern "C" void kernel_launch(void* const* d_in, const int* in_sizes, int n_in,
                              void* d_out, int out_size, void* d_ws, size_t ws_size,
                              hipStream_t stream)
{
    const float* x  = (const float*)d_in[0];
    const float* W1 = (const float*)d_in[1];
    const float* b1 = (const float*)d_in[2];
    const float* W2 = (const float*)d_in[3];
    const float* b2 = (const float*)d_in[4];
    const float* cb = (const float*)d_in[5];
    const float* W3 = (const float*)d_in[6];
    const float* b3 = (const float*)d_in[7];
    const float* W4 = (const float*)d_in[8];
    const float* b4 = (const float*)d_in[9];
    float* out = (float*)d_out;
    char*  ws  = (char*)d_ws;

    u16*    h1hi    = (u16*)   (ws);                      // 134217728
    u16*    h1lo    = (u16*)   (ws + 134217728);          // 134217728 (reused as h2b)
    u16*    h2b     = (u16*)   (ws + 134217728);
    u16*    zb      = (u16*)   (ws + 268435456);          // 67108864
    float*  pd1     = (float*) (ws + 335544320);          // 4194304
    int*    pi1     = (int*)   (ws + 339738624);          // 4194304
    float*  pd2     = (float*) (ws + 343932928);          // 4194304
    float*  znorm   = (float*) (ws + 348127232);          // 524288
    float*  rowloss = (float*) (ws + 348651520);          // 524288
    int*    idxi    = (int*)   (ws + 349175808);          // 524288
    int*    list    = (int*)   (ws + 349700096);          // 524288
    int*    rcnt    = (int*)   (ws + 350224384);          // 64
    double* lossa   = (double*)(ws + 350224448);          // 64
    u16*    W1Thi   = (u16*)   (ws + 350224512);          // 786432
    u16*    W1Tlo   = (u16*)   (ws + 351010944);          // 786432
    u16*    WcThi   = (u16*)   (ws + 351797376);          // 524288
    u16*    WcTlo   = (u16*)   (ws + 352321664);          // 524288
    u16*    W2Th    = (u16*)   (ws + 352845952);          // 262144
    u16*    cbB     = (u16*)   (ws + 353108096);          // 262144
    u16*    W3T     = (u16*)   (ws + 353370240);          // 262144
    u16*    W4T     = (u16*)   (ws + 353632384);          // 786432
    float*  bc      = (float*) (ws + 354418816);          // 2048
    float*  cnorm   = (float*) (ws + 354420864);          // 2048
    float*  cbT     = (float*) (ws + 354422912);          // 524288

    float* idxf    = out + (size_t)N_ROWS * DIN;
    float* lossout = idxf + N_ROWS;

    hipMemsetAsync(ws + 350224384, 0, 128, stream);       // rcnt + lossa

    // prep
    transpose_cb_kernel<<<512, 256, 0, stream>>>(cb, cbT);
    cnorm_np_kernel<<<8, 64, 0, stream>>>(cb, cnorm);
    cast_bf16_kernel<<<(KC*DCODE)/256, 256, 0, stream>>>(cb, cbB, KC*DCODE);
    castT_bf16_kernel<<<(DCODE*DHID)/256, 256, 0, stream>>>(W3, W3T, DCODE, DHID);
    castT_bf16_kernel<<<(DHID*DIN)/256, 256, 0, stream>>>(W4, W4T, DHID, DIN);
    prep_W1T<<<(DHID*DIN)/256, 256, 0, stream>>>(W1, W1Thi, W1Tlo);
    prep_Wc<<<(KC*DHID)/256, 256, 0, stream>>>(W2, cb, WcThi, WcTlo);
    prep_bc<<<2, 256, 0, stream>>>(b2, cb, bc);
    prep_W2T<<<(DCODE*DHID)/256, 256, 0, stream>>>(W2, W2Th);

    // fast index path: split-2 bf16 MFMA
    split2_gemm<0><<<dim3(DHID/128, N_ROWS/128), 256, 0, stream>>>(
        x, nullptr, nullptr, W1Thi, W1Tlo, b1, nullptr,
        h1hi, h1lo, nullptr, nullptr, nullptr, N_ROWS, DHID, DIN);
    split2_gemm<1><<<dim3(KC/128, N_ROWS/128), 256, 0, stream>>>(
        nullptr, h1hi, h1lo, WcThi, WcTlo, bc, cnorm,
        nullptr, nullptr, pd1, pi1, pd2, N_ROWS, KC, DHID);

    // z (bf16, loss only) + znorm
    mfma_gemm<false, false, true><<<dim3(DCODE/128, N_ROWS/128), 256, 0, stream>>>(
        h1hi, W2Th, b2, nullptr, (void*)zb, N_ROWS, DCODE, DHID);
    znorm_bf16_kernel<<<N_ROWS/4, 256, 0, stream>>>(zb, znorm);

    // merge + flag + bitwise recompute of contested rows
    final_argmin_flag<<<N_ROWS/256, 256, 0, stream>>>(
        pd1, pi1, pd2, znorm, idxf, idxi, rowloss, rcnt, list);
    recompute_kernel<<<2048, 512, 0, stream>>>(
        x, W1, b1, W2, b2, cbT, cnorm, rcnt, list, idxf, idxi);

    // decoder (bf16 MFMA; h1lo dead -> h2b aliases it)
    mfma_gemm<true,  true,  true ><<<dim3(DHID/128, N_ROWS/128), 256, 0, stream>>>(
        cbB, W3T, b3, idxi, (void*)h2b, N_ROWS, DHID, DCODE);
    mfma_gemm<false, false, false><<<dim3(DIN/128,  N_ROWS/128), 256, 0, stream>>>(
        h2b, W4T, b4, nullptr, (void*)out, N_ROWS, DIN, DHID);

    loss_reduce_kernel<<<256, 256, 0, stream>>>(rowloss, lossa, N_ROWS);
    finalize_kernel<<<1, 1, 0, stream>>>(lossa, lossout);
}

// Round 7
// 1138.350 us; speedup vs baseline: 10.8073x; 1.0286x over previous
//
#include <hip/hip_runtime.h>
#include <hip/hip_bf16.h>
#include <math.h>

#define N_ROWS 131072
#define DIN    768
#define DHID   512
#define DCODE  256
#define KC     512
#define NFUSE  768      // KC + DCODE (dots cols + z cols)
#define TAU    5e-3f

typedef short short8 __attribute__((ext_vector_type(8)));
typedef float f32x4  __attribute__((ext_vector_type(4)));
typedef unsigned int   u32;
typedef unsigned short u16;

__device__ __forceinline__ void gload16(const void* g, void* l) {
    __builtin_amdgcn_global_load_lds(
        (const __attribute__((address_space(1))) u32*)g,
        (__attribute__((address_space(3))) u32*)l, 16, 0, 0);
}

__device__ __forceinline__ u16 f2bf(float f) {
    u32 u = __builtin_bit_cast(u32, f);
    return (u16)((u + 0x7fffu + ((u >> 16) & 1u)) >> 16);
}
__device__ __forceinline__ float bf2f(u16 h) {
    u32 u = ((u32)h) << 16;
    return __builtin_bit_cast(float, u);
}

// m157-form bijective XCD swizzle (all grids have nwg % 8 == 0)
__device__ __forceinline__ void xcd_swizzle(int& bxs, int& bys) {
    const int GX  = gridDim.x;
    const int nwg = GX * gridDim.y;
    const int lid = blockIdx.y * GX + blockIdx.x;
    const int chunk = nwg >> 3;
    const int nlid  = (lid & 7) * chunk + (lid >> 3);
    bxs = nlid % GX;
    bys = nlid / GX;
}

// hi/lo bf16 split of a float4, written to two 8B LDS slots
__device__ __forceinline__ void split_write(char* hidst, char* lodst, float4 v) {
    u16 h0 = f2bf(v.x), h1 = f2bf(v.y), h2 = f2bf(v.z), h3 = f2bf(v.w);
    u16 l0 = f2bf(__fsub_rn(v.x, bf2f(h0)));
    u16 l1 = f2bf(__fsub_rn(v.y, bf2f(h1)));
    u16 l2 = f2bf(__fsub_rn(v.z, bf2f(h2)));
    u16 l3 = f2bf(__fsub_rn(v.w, bf2f(h3)));
    ushort4 hi; hi.x = h0; hi.y = h1; hi.z = h2; hi.w = h3;
    ushort4 lo; lo.x = l0; lo.y = l1; lo.z = l2; lo.w = l3;
    *(ushort4*)hidst = hi;
    *(ushort4*)lodst = lo;
}

// ---------------------------------------------------------------------------
// Split-2 bf16 MFMA GEMM, 128x128 tile, BK=32, 4 waves (2x2).
// SINGLE-buffer 32KB LDS, 2 barriers/K-step (m97 template), 4 blocks/CU.
// C = A@B^T(+bias), A = Ahi+Alo, B = Bhi+Blo; 3 MFMA per fragment pair.
// LDS rows 128B = [hi 4 slots | lo 4 slots], XOR-swizzled by row&7.
// EPI=0 (H1): A = f32 (reg-stage + split), epilogue relu+bias -> hi/lo bf16.
// EPI=1 (DOTS+Z): A = bf16 pair. Col-tiles 0-3 (codes): dist top-2 lex-min
//   partials. Col-tiles 4-5 (z): znorm partials only (z never materialized).
// ---------------------------------------------------------------------------
template<int EPI>
__global__ __launch_bounds__(256, 3)
void split2_gemm(const float* __restrict__ Af32,
                 const u16* __restrict__ Ahi, const u16* __restrict__ Alo,
                 const u16* __restrict__ Bhi, const u16* __restrict__ Blo,
                 const float* __restrict__ bias,
                 const float* __restrict__ cnorm,
                 u16* __restrict__ Chi, u16* __restrict__ Clo,
                 float* __restrict__ pd1, int* __restrict__ pi1,
                 float* __restrict__ pd2, float* __restrict__ pzn,
                 int M, int N, int K)
{
    __shared__ char lds[32768];   // A pair @0 (16K), B pair @16384 (16K)
    const int t = threadIdx.x, lane = t & 63, wid = t >> 6;
    const int wm = wid >> 1, wn = wid & 1;
    int bxs, bys; xcd_swizzle(bxs, bys);
    const int bm = bys * 128, bn = bxs * 128;

    // staging: 16 chunks of 1KB (8 rows x 128B); lane: row sr, slot sl (pre-swz)
    const int sr = lane >> 3, qq = lane & 7, sl = qq ^ sr;
    const u16* bsrc[4];
    #pragma unroll
    for (int c = 0; c < 4; c++) {
        int row = bn + (wid * 4 + c) * 8 + sr;
        const u16* base = (sl < 4) ? Bhi : Blo;
        bsrc[c] = base + (size_t)row * K + (sl & 3) * 8;
    }
    const u16* asrc[4];
    const float* a32src[4];
    int adhi[4], adlo[4];
    if constexpr (EPI == 1) {
        #pragma unroll
        for (int c = 0; c < 4; c++) {
            int row = bm + (wid * 4 + c) * 8 + sr;
            const u16* base = (sl < 4) ? Ahi : Alo;
            asrc[c] = base + (size_t)row * K + (sl & 3) * 8;
        }
    } else {
        #pragma unroll
        for (int c = 0; c < 4; c++) {
            int id = c * 256 + t;
            int row = id >> 3, k4 = id & 7;
            a32src[c] = Af32 + (size_t)(bm + row) * K + k4 * 4;
            int s = k4 >> 1, hf = k4 & 1;
            adhi[c] = row * 128 + ((s ^ (row & 7)) << 4) + hf * 8;
            adlo[c] = row * 128 + (((s | 4) ^ (row & 7)) << 4) + hf * 8;
        }
    }

    f32x4 acc[4][4];
    #pragma unroll
    for (int i = 0; i < 4; i++)
        #pragma unroll
        for (int j = 0; j < 4; j++) acc[i][j] = (f32x4)0.f;

    const int fr = lane & 15, sw = lane & 7;
    const int offhi = (((lane >> 4) ^ sw) << 4);
    const int offlo = ((((lane >> 4) | 4) ^ sw) << 4);
    const int arow = wm * 64 + fr, brow = wn * 64 + fr;
    const int NT = K >> 5;

    for (int tt = 0; tt < NT; tt++) {
        __syncthreads();              // previous tile's LDS reads done
        const int kadv = tt * 32;
        #pragma unroll
        for (int c = 0; c < 4; c++)
            gload16(bsrc[c] + kadv, lds + 16384 + (wid * 4 + c) * 1024);
        if constexpr (EPI == 1) {
            #pragma unroll
            for (int c = 0; c < 4; c++)
                gload16(asrc[c] + kadv, lds + (wid * 4 + c) * 1024);
        } else {
            #pragma unroll
            for (int c = 0; c < 4; c++) {
                float4 v = *(const float4*)(a32src[c] + kadv);
                split_write(lds + adhi[c], lds + adlo[c], v);
            }
        }
        __syncthreads();              // drains vmcnt/lgkm: tile staged
        char* ab  = lds;
        char* bb2 = lds + 16384;
        short8 ah[4], al[4];
        #pragma unroll
        for (int i = 0; i < 4; i++) {
            ah[i] = *(const short8*)(ab + ((arow + i * 16) << 7) + offhi);
            al[i] = *(const short8*)(ab + ((arow + i * 16) << 7) + offlo);
        }
        #pragma unroll
        for (int j = 0; j < 4; j++) {
            short8 bh = *(const short8*)(bb2 + ((brow + j * 16) << 7) + offhi);
            short8 bl = *(const short8*)(bb2 + ((brow + j * 16) << 7) + offlo);
            #pragma unroll
            for (int i = 0; i < 4; i++) {
                acc[i][j] = __builtin_amdgcn_mfma_f32_16x16x32_bf16(ah[i], bh, acc[i][j], 0, 0, 0);
                acc[i][j] = __builtin_amdgcn_mfma_f32_16x16x32_bf16(al[i], bh, acc[i][j], 0, 0, 0);
                acc[i][j] = __builtin_amdgcn_mfma_f32_16x16x32_bf16(ah[i], bl, acc[i][j], 0, 0, 0);
            }
        }
    }

    if constexpr (EPI == 1) {
        const int ec = lane & 15, g = lane >> 4;
        if (bxs < 4) {
            // code columns: dist top-2 partials
            float cnv[4], bcv[4];
            #pragma unroll
            for (int j = 0; j < 4; j++) {
                int c = bn + wn * 64 + j * 16 + ec;
                cnv[j] = cnorm[c]; bcv[j] = bias[c];
            }
            const int strip = bxs * 2 + wn;
            #pragma unroll
            for (int i = 0; i < 4; i++) {
                #pragma unroll
                for (int e = 0; e < 4; e++) {
                    float d1 = INFINITY, d2 = INFINITY; int i1 = 0x7fffffff;
                    #pragma unroll
                    for (int j = 0; j < 4; j++) {
                        int c = bn + wn * 64 + j * 16 + ec;
                        float d = __fsub_rn(cnv[j],
                                  __fmul_rn(2.0f, __fadd_rn(acc[i][j][e], bcv[j])));
                        if (d < d1 || (d == d1 && c < i1)) { d2 = d1; d1 = d; i1 = c; }
                        else if (d < d2) d2 = d;
                    }
                    #pragma unroll
                    for (int m = 1; m < 16; m <<= 1) {
                        float od1 = __shfl_xor(d1, m);
                        int   oi1 = __shfl_xor(i1, m);
                        float od2 = __shfl_xor(d2, m);
                        if (od1 < d1 || (od1 == d1 && oi1 < i1)) {
                            d2 = fminf(d1, od2); d1 = od1; i1 = oi1;
                        } else d2 = fminf(d2, od1);
                    }
                    if (ec == 0) {
                        int r = bm + wm * 64 + i * 16 + g * 4 + e;
                        pd1[(size_t)strip * M + r] = d1;
                        pi1[(size_t)strip * M + r] = i1;
                        pd2[(size_t)strip * M + r] = d2;
                    }
                }
            }
        } else {
            // z columns: znorm partials (z = acc + b2[col]; never stored)
            float bcv[4];
            #pragma unroll
            for (int j = 0; j < 4; j++)
                bcv[j] = bias[bn + wn * 64 + j * 16 + ec];
            const int zs = (bxs - 4) * 2 + wn;
            #pragma unroll
            for (int i = 0; i < 4; i++) {
                #pragma unroll
                for (int e = 0; e < 4; e++) {
                    float s = 0.f;
                    #pragma unroll
                    for (int j = 0; j < 4; j++) {
                        float zv = acc[i][j][e] + bcv[j];
                        s = fmaf(zv, zv, s);
                    }
                    #pragma unroll
                    for (int m = 1; m < 16; m <<= 1) s += __shfl_xor(s, m);
                    if (ec == 0) {
                        int r = bm + wm * 64 + i * 16 + g * 4 + e;
                        pzn[(size_t)zs * M + r] = s;
                    }
                }
            }
        }
        return;
    } else {
        const int er = (lane >> 4) * 4, ec = lane & 15;
        #pragma unroll
        for (int j = 0; j < 4; j++) {
            int col = bn + wn * 64 + j * 16 + ec;
            float bb = bias[col];
            #pragma unroll
            for (int i = 0; i < 4; i++) {
                #pragma unroll
                for (int e = 0; e < 4; e++) {
                    int r = bm + wm * 64 + i * 16 + er + e;
                    float v = fmaxf(__fadd_rn(acc[i][j][e], bb), 0.f);
                    u16 hi = f2bf(v);
                    u16 lo = f2bf(__fsub_rn(v, bf2f(hi)));
                    Chi[(size_t)r * N + col] = hi;
                    Clo[(size_t)r * N + col] = lo;
                }
            }
        }
    }
}

// ---------------------------------------------------------------------------
// Plain bf16 MFMA GEMM (decoder; lenient). Single-buffer 32KB, BK=64,
// 2 barriers/K-step, 4 blocks/CU. C = act(A[M,K] @ BT[N,K]^T + bias).
// ---------------------------------------------------------------------------
template<bool RELU, bool GATHER, bool OUT_BF16>
__global__ __launch_bounds__(256, 3)
void mfma_gemm(const u16* __restrict__ A, const u16* __restrict__ BT,
               const float* __restrict__ bias, const int* __restrict__ rowidx,
               void* __restrict__ Cout, int M, int N, int K)
{
    __shared__ char lds[32768];
    const int t    = threadIdx.x;
    const int lane = t & 63, wid = t >> 6;
    const int wm   = wid >> 1, wn = wid & 1;
    int bxs, bys;
    xcd_swizzle(bxs, bys);
    const int bm = bys * 128, bn = bxs * 128;

    const int sr = lane >> 3;
    const int sc = ((lane & 7) ^ sr) * 8;
    const u16* aptr[4];
    const u16* bptr[4];
    #pragma unroll
    for (int c = 0; c < 4; c++) {
        int gc   = wid * 4 + c;
        int arow = bm + 8 * gc + sr;
        if (GATHER) arow = rowidx[arow];
        aptr[c] = A  + (size_t)arow * K + sc;
        int brow = bn + 8 * gc + sr;
        bptr[c] = BT + (size_t)brow * K + sc;
    }

    f32x4 acc[4][4];
    #pragma unroll
    for (int i = 0; i < 4; i++)
        #pragma unroll
        for (int j = 0; j < 4; j++) acc[i][j] = (f32x4)0.f;

    const int koff0 = (16 * (lane >> 4))      ^ ((lane & 7) << 4);
    const int koff1 = (64 + 16 * (lane >> 4)) ^ ((lane & 7) << 4);
    const int arow_rd = wm * 64 + (lane & 15);
    const int brow_rd = wn * 64 + (lane & 15);

    const int NT = K >> 6;
    for (int tt = 0; tt < NT; tt++) {
        __syncthreads();
        const int k0 = tt << 6;
        #pragma unroll
        for (int c = 0; c < 4; c++) {
            int gc = wid * 4 + c;
            gload16(aptr[c] + k0, lds + gc * 1024);
            gload16(bptr[c] + k0, lds + 16384 + gc * 1024);
        }
        __syncthreads();
        char* ldsA = lds;
        char* ldsB = lds + 16384;
        #pragma unroll
        for (int kk = 0; kk < 2; kk++) {
            const int ko = kk ? koff1 : koff0;
            short8 af[4], bfr[4];
            #pragma unroll
            for (int i = 0; i < 4; i++)
                af[i]  = *(const short8*)(ldsA + (arow_rd + i * 16) * 128 + ko);
            #pragma unroll
            for (int j = 0; j < 4; j++)
                bfr[j] = *(const short8*)(ldsB + (brow_rd + j * 16) * 128 + ko);
            #pragma unroll
            for (int i = 0; i < 4; i++)
                #pragma unroll
                for (int j = 0; j < 4; j++)
                    acc[i][j] = __builtin_amdgcn_mfma_f32_16x16x32_bf16(
                        af[i], bfr[j], acc[i][j], 0, 0, 0);
        }
    }

    const int er = (lane >> 4) * 4;
    const int ec = lane & 15;
    #pragma unroll
    for (int j = 0; j < 4; j++) {
        int col  = bn + wn * 64 + j * 16 + ec;
        float bb = bias[col];
        #pragma unroll
        for (int i = 0; i < 4; i++) {
            #pragma unroll
            for (int e = 0; e < 4; e++) {
                int r   = bm + wm * 64 + i * 16 + er + e;
                float v = acc[i][j][e] + bb;
                if (RELU) v = fmaxf(v, 0.f);
                if (OUT_BF16) ((u16*)Cout)[(size_t)r * N + col]  = f2bf(v);
                else          ((float*)Cout)[(size_t)r * N + col] = v;
            }
        }
    }
}

// ---------------------------------------------------------------------------
// Prep kernels
// ---------------------------------------------------------------------------
__global__ void transpose_cb_kernel(const float* __restrict__ cb, float* __restrict__ cbT)
{
    int tid = blockIdx.x * 256 + threadIdx.x;   // 512*256
    int k = tid >> 8;
    int d = tid & 255;
    cbT[(size_t)d * KC + k] = cb[(size_t)k * DCODE + d];
}

__global__ void cast_bf16_kernel(const float* __restrict__ in, u16* __restrict__ out, int n)
{
    int i = blockIdx.x * 256 + threadIdx.x;
    if (i < n) out[i] = f2bf(in[i]);
}

// in [K][N] fp32 -> out [N][K] bf16
__global__ void castT_bf16_kernel(const float* __restrict__ in, u16* __restrict__ out,
                                  int K, int N)
{
    int i = blockIdx.x * 256 + threadIdx.x;
    if (i >= K * N) return;
    int n = i / K, k = i - n * K;
    out[i] = f2bf(in[(size_t)k * N + n]);
}

// W1 [768][512] -> W1T hi/lo [512][768]
__global__ void prep_W1T(const float* __restrict__ W1, u16* __restrict__ Thi,
                         u16* __restrict__ Tlo)
{
    int id = blockIdx.x * 256 + threadIdx.x;    // 512*768
    if (id >= DHID * DIN) return;
    int n = id / DIN, k = id - n * DIN;
    float v = W1[(size_t)k * DHID + n];
    u16 hi = f2bf(v);
    Thi[id] = hi;
    Tlo[id] = f2bf(__fsub_rn(v, bf2f(hi)));
}

// WfT rows 0-511: WcT[n][h] = sum_t W2[h][t]*cb[n][t] (fp64), split hi/lo
__global__ void prep_Wc(const float* __restrict__ W2, const float* __restrict__ cb,
                        u16* __restrict__ Thi, u16* __restrict__ Tlo)
{
    int id = blockIdx.x * 256 + threadIdx.x;    // 512*512
    int n = id & 511, h = id >> 9;
    double acc = 0.0;
    for (int tt2 = 0; tt2 < DCODE; tt2++)
        acc += (double)W2[(size_t)h * DCODE + tt2] * (double)cb[(size_t)n * DCODE + tt2];
    float v = (float)acc;
    u16 hi = f2bf(v);
    Thi[(size_t)n * DHID + h] = hi;
    Tlo[(size_t)n * DHID + h] = f2bf(__fsub_rn(v, bf2f(hi)));
}

// WfT rows 512-767: W2 [512][256] -> WfT[512+t2][h], split hi/lo
__global__ void prep_W2T_pair(const float* __restrict__ W2, u16* __restrict__ Thi,
                              u16* __restrict__ Tlo)
{
    int id = blockIdx.x * 256 + threadIdx.x;    // 256*512
    if (id >= DCODE * DHID) return;
    int t2 = id >> 9, h = id & 511;
    float v = W2[(size_t)h * DCODE + t2];
    u16 hi = f2bf(v);
    Thi[(size_t)(KC + t2) * DHID + h] = hi;
    Tlo[(size_t)(KC + t2) * DHID + h] = f2bf(__fsub_rn(v, bf2f(hi)));
}

// bcf[0..511] = fp64 b2·cb[n]; bcf[512..767] = b2[n-512]
__global__ void prep_bcf(const float* __restrict__ b2, const float* __restrict__ cb,
                         float* __restrict__ bcf)
{
    int n = blockIdx.x * 256 + threadIdx.x;
    if (n >= NFUSE) return;
    if (n < KC) {
        double acc = 0.0;
        for (int tt2 = 0; tt2 < DCODE; tt2++)
            acc += (double)b2[tt2] * (double)cb[(size_t)n * DCODE + tt2];
        bcf[n] = (float)acc;
    } else {
        bcf[n] = b2[n - KC];
    }
}

// ||c_k||^2 replicating numpy float32 pairwise-summation bitwise (ref-exact).
__global__ void cnorm_np_kernel(const float* __restrict__ cb, float* __restrict__ cnorm)
{
    int k = blockIdx.x * 64 + threadIdx.x;
    if (k >= KC) return;
    const float* c = cb + (size_t)k * DCODE;
    float bsum[2];
    #pragma unroll
    for (int b = 0; b < 2; b++) {
        const float* a = c + b * 128;
        float r[8];
        #pragma unroll
        for (int j = 0; j < 8; j++) r[j] = __fmul_rn(a[j], a[j]);
        for (int i = 8; i < 128; i += 8)
            #pragma unroll
            for (int j = 0; j < 8; j++)
                r[j] = __fadd_rn(r[j], __fmul_rn(a[i + j], a[i + j]));
        bsum[b] = __fadd_rn(
            __fadd_rn(__fadd_rn(r[0], r[1]), __fadd_rn(r[2], r[3])),
            __fadd_rn(__fadd_rn(r[4], r[5]), __fadd_rn(r[6], r[7])));
    }
    cnorm[k] = __fadd_rn(bsum[0], bsum[1]);
}

// ---------------------------------------------------------------------------
// Final merge of 8 strip top-2 partials + 4 znorm partials; flag gap < TAU.
// ---------------------------------------------------------------------------
__global__ void final_argmin_flag(const float* __restrict__ pd1,
                                  const int* __restrict__ pi1,
                                  const float* __restrict__ pd2,
                                  const float* __restrict__ pzn,
                                  float* __restrict__ idx_f,
                                  int* __restrict__ idx_i,
                                  float* __restrict__ rowloss,
                                  int* __restrict__ cnt,
                                  int* __restrict__ list)
{
    int r = blockIdx.x * 256 + threadIdx.x;
    if (r >= N_ROWS) return;
    float d1 = pd1[r]; int i1 = pi1[r]; float d2 = pd2[r];
    #pragma unroll
    for (int b = 1; b < 8; b++) {
        float od1 = pd1[(size_t)b * N_ROWS + r];
        int   oi1 = pi1[(size_t)b * N_ROWS + r];
        float od2 = pd2[(size_t)b * N_ROWS + r];
        if (od1 < d1 || (od1 == d1 && oi1 < i1)) {
            d2 = fminf(d1, od2); d1 = od1; i1 = oi1;
        } else d2 = fminf(d2, od1);
    }
    float zn = pzn[r] + pzn[(size_t)N_ROWS + r]
             + pzn[(size_t)2 * N_ROWS + r] + pzn[(size_t)3 * N_ROWS + r];
    idx_f[r]   = (float)i1;
    idx_i[r]   = i1;
    rowloss[r] = zn + d1;
    if (d2 - d1 < TAU) {
        int p = atomicAdd(cnt, 1);
        list[p] = r;
    }
}

// ---------------------------------------------------------------------------
// Bitwise fp32 recompute for contested rows (exact round-2 chain numerics).
// ---------------------------------------------------------------------------
__global__ __launch_bounds__(512)
void recompute_kernel(const float* __restrict__ x,  const float* __restrict__ W1,
                      const float* __restrict__ b1, const float* __restrict__ W2,
                      const float* __restrict__ b2, const float* __restrict__ cbT,
                      const float* __restrict__ cnorm,
                      const int* __restrict__ cnt,  const int* __restrict__ list,
                      float* __restrict__ idx_f,    int* __restrict__ idx_i)
{
    __shared__ float xs[8][DIN];
    __shared__ float h1s[8][DHID];
    __shared__ float zs[8][DCODE];
    __shared__ float swd[8][8];
    __shared__ int   swi[8][8];
    __shared__ int   rls[8];
    const int t = threadIdx.x;
    const int n = *cnt;

    for (int base = blockIdx.x * 8; base < n; base += gridDim.x * 8) {
        __syncthreads();
        if (t < 8) rls[t] = (base + t < n) ? list[base + t] : -1;
        __syncthreads();
        #pragma unroll
        for (int rr = 0; rr < 8; rr++) {
            int row = rls[rr];
            if (row >= 0)
                for (int i = t; i < DIN; i += 512)
                    xs[rr][i] = x[(size_t)row * DIN + i];
        }
        __syncthreads();
        {
            float acc[8] = {0.f,0.f,0.f,0.f,0.f,0.f,0.f,0.f};
            for (int i = 0; i < DIN; i++) {
                float w = W1[(size_t)i * DHID + t];
                #pragma unroll
                for (int rr = 0; rr < 8; rr++)
                    acc[rr] = fmaf(xs[rr][i], w, acc[rr]);
            }
            float bb = b1[t];
            #pragma unroll
            for (int rr = 0; rr < 8; rr++)
                h1s[rr][t] = fmaxf(__fadd_rn(acc[rr], bb), 0.f);
        }
        __syncthreads();
        {
            int half = t >> 8, t2 = t & 255;
            float acc[4] = {0.f,0.f,0.f,0.f};
            for (int h = 0; h < DHID; h++) {
                float w = W2[(size_t)h * DCODE + t2];
                #pragma unroll
                for (int q2 = 0; q2 < 4; q2++)
                    acc[q2] = fmaf(h1s[half * 4 + q2][h], w, acc[q2]);
            }
            float bb = b2[t2];
            #pragma unroll
            for (int q2 = 0; q2 < 4; q2++)
                zs[half * 4 + q2][t2] = __fadd_rn(acc[q2], bb);
        }
        __syncthreads();
        {
            float acc[8] = {0.f,0.f,0.f,0.f,0.f,0.f,0.f,0.f};
            for (int d = 0; d < DCODE; d++) {
                float c = cbT[(size_t)d * KC + t];
                #pragma unroll
                for (int rr = 0; rr < 8; rr++)
                    acc[rr] = fmaf(zs[rr][d], c, acc[rr]);
            }
            float cn = cnorm[t];
            #pragma unroll
            for (int rr = 0; rr < 8; rr++) {
                float d = __fsub_rn(cn, __fmul_rn(2.0f, acc[rr]));
                int ii = t;
                #pragma unroll
                for (int m = 1; m < 64; m <<= 1) {
                    float od = __shfl_xor(d, m);
                    int   oi = __shfl_xor(ii, m);
                    if (od < d || (od == d && oi < ii)) { d = od; ii = oi; }
                }
                if ((t & 63) == 0) { swd[rr][t >> 6] = d; swi[rr][t >> 6] = ii; }
            }
        }
        __syncthreads();
        if (t < 8) {
            int row = rls[t];
            if (row >= 0) {
                float d = swd[t][0]; int ii = swi[t][0];
                #pragma unroll
                for (int w = 1; w < 8; w++) {
                    float od = swd[t][w]; int oi = swi[t][w];
                    if (od < d || (od == d && oi < ii)) { d = od; ii = oi; }
                }
                idx_i[row] = ii;
                idx_f[row] = (float)ii;
            }
        }
    }
}

// ---------------------------------------------------------------------------
__global__ void loss_reduce_kernel(const float* __restrict__ rowloss,
                                   double* __restrict__ acc, int n)
{
    double s = 0.0;
    for (int i = blockIdx.x * blockDim.x + threadIdx.x; i < n; i += gridDim.x * blockDim.x)
        s += (double)rowloss[i];
    for (int off = 32; off; off >>= 1) s += __shfl_xor(s, off);
    __shared__ double red[4];
    int lane = threadIdx.x & 63, wave = threadIdx.x >> 6;
    if (lane == 0) red[wave] = s;
    __syncthreads();
    if (threadIdx.x == 0) {
        double b = red[0] + red[1] + red[2] + red[3];
        atomicAdd(acc, b);
    }
}

__global__ void finalize_kernel(const double* __restrict__ acc, float* __restrict__ out)
{
    out[0] = (float)(acc[0] / ((double)N_ROWS * (double)DCODE));
}

// ---------------------------------------------------------------------------
extern "C" void kernel_launch(void* const* d_in, const int* in_sizes, int n_in,
                              void* d_out, int out_size, void* d_ws, size_t ws_size,
                              hipStream_t stream)
{
    const float* x  = (const float*)d_in[0];
    const float* W1 = (const float*)d_in[1];
    const float* b1 = (const float*)d_in[2];
    const float* W2 = (const float*)d_in[3];
    const float* b2 = (const float*)d_in[4];
    const float* cb = (const float*)d_in[5];
    const float* W3 = (const float*)d_in[6];
    const float* b3 = (const float*)d_in[7];
    const float* W4 = (const float*)d_in[8];
    const float* b4 = (const float*)d_in[9];
    float* out = (float*)d_out;
    char*  ws  = (char*)d_ws;

    u16*    h1hi    = (u16*)   (ws);                      // 134217728
    u16*    h1lo    = (u16*)   (ws + 134217728);          // 134217728 (later h2b)
    u16*    h2b     = (u16*)   (ws + 134217728);
    float*  pd1     = (float*) (ws + 268435456);          // 4194304
    int*    pi1     = (int*)   (ws + 272629760);          // 4194304
    float*  pd2     = (float*) (ws + 276824064);          // 4194304
    float*  pzn     = (float*) (ws + 281018368);          // 2097152
    float*  rowloss = (float*) (ws + 283115520);          // 524288
    int*    idxi    = (int*)   (ws + 283639808);          // 524288
    int*    list    = (int*)   (ws + 284164096);          // 524288
    int*    rcnt    = (int*)   (ws + 284688384);          // 64
    double* lossa   = (double*)(ws + 284688448);          // 64
    u16*    W1Thi   = (u16*)   (ws + 284688512);          // 786432
    u16*    W1Tlo   = (u16*)   (ws + 285474944);          // 786432
    u16*    WfThi   = (u16*)   (ws + 286261376);          // 786432 (768x512)
    u16*    WfTlo   = (u16*)   (ws + 287047808);          // 786432
    u16*    cbB     = (u16*)   (ws + 287834240);          // 262144
    u16*    W3T     = (u16*)   (ws + 288096384);          // 262144
    u16*    W4T     = (u16*)   (ws + 288358528);          // 786432
    float*  bcf     = (float*) (ws + 289144960);          // 3072
    float*  cnorm   = (float*) (ws + 289148032);          // 2048
    float*  cbT     = (float*) (ws + 289150080);          // 524288

    float* idxf    = out + (size_t)N_ROWS * DIN;
    float* lossout = idxf + N_ROWS;

    hipMemsetAsync(ws + 284688384, 0, 128, stream);       // rcnt + lossa

    // prep
    transpose_cb_kernel<<<512, 256, 0, stream>>>(cb, cbT);
    cnorm_np_kernel<<<8, 64, 0, stream>>>(cb, cnorm);
    cast_bf16_kernel<<<(KC*DCODE)/256, 256, 0, stream>>>(cb, cbB, KC*DCODE);
    castT_bf16_kernel<<<(DCODE*DHID)/256, 256, 0, stream>>>(W3, W3T, DCODE, DHID);
    castT_bf16_kernel<<<(DHID*DIN)/256, 256, 0, stream>>>(W4, W4T, DHID, DIN);
    prep_W1T<<<(DHID*DIN)/256, 256, 0, stream>>>(W1, W1Thi, W1Tlo);
    prep_Wc<<<(KC*DHID)/256, 256, 0, stream>>>(W2, cb, WfThi, WfTlo);
    prep_W2T_pair<<<(DCODE*DHID)/256, 256, 0, stream>>>(W2, WfThi, WfTlo);
    prep_bcf<<<3, 256, 0, stream>>>(b2, cb, bcf);

    // fast index path: split-2 bf16 MFMA
    split2_gemm<0><<<dim3(DHID/128, N_ROWS/128), 256, 0, stream>>>(
        x, nullptr, nullptr, W1Thi, W1Tlo, b1, nullptr,
        h1hi, h1lo, nullptr, nullptr, nullptr, nullptr, N_ROWS, DHID, DIN);
    // dots (cols 0-511) + znorm (cols 512-767) fused
    split2_gemm<1><<<dim3(NFUSE/128, N_ROWS/128), 256, 0, stream>>>(
        nullptr, h1hi, h1lo, WfThi, WfTlo, bcf, cnorm,
        nullptr, nullptr, pd1, pi1, pd2, pzn, N_ROWS, NFUSE, DHID);

    // merge + flag + bitwise recompute of contested rows
    final_argmin_flag<<<N_ROWS/256, 256, 0, stream>>>(
        pd1, pi1, pd2, pzn, idxf, idxi, rowloss, rcnt, list);
    recompute_kernel<<<2048, 512, 0, stream>>>(
        x, W1, b1, W2, b2, cbT, cnorm, rcnt, list, idxf, idxi);

    // decoder (bf16 MFMA; h1lo dead -> h2b aliases it)
    mfma_gemm<true,  true,  true ><<<dim3(DHID/128, N_ROWS/128), 256, 0, stream>>>(
        cbB, W3T, b3, idxi, (void*)h2b, N_ROWS, DHID, DCODE);
    mfma_gemm<false, false, false><<<dim3(DIN/128,  N_ROWS/128), 256, 0, stream>>>(
        h2b, W4T, b4, nullptr, (void*)out, N_ROWS, DIN, DHID);

    loss_reduce_kernel<<<256, 256, 0, stream>>>(rowloss, lossa, N_ROWS);
    finalize_kernel<<<1, 1, 0, stream>>>(lossa, lossout);
}

// Round 8
// 941.984 us; speedup vs baseline: 13.0601x; 1.2085x over previous
//
#include <hip/hip_runtime.h>
#include <hip/hip_bf16.h>
#include <math.h>

#define N_ROWS 131072
#define DIN    768
#define DHID   512
#define DCODE  256
#define KC     512
#define NFUSE  768      // KC + DCODE (dots cols + z cols)
#define TAU    5e-3f

typedef short short8 __attribute__((ext_vector_type(8)));
typedef float f32x4  __attribute__((ext_vector_type(4)));
typedef unsigned int   u32;
typedef unsigned short u16;

__device__ __forceinline__ void gload16(const void* g, void* l) {
    __builtin_amdgcn_global_load_lds(
        (const __attribute__((address_space(1))) u32*)g,
        (__attribute__((address_space(3))) u32*)l, 16, 0, 0);
}

__device__ __forceinline__ u16 f2bf(float f) {
    u32 u = __builtin_bit_cast(u32, f);
    return (u16)((u + 0x7fffu + ((u >> 16) & 1u)) >> 16);
}
__device__ __forceinline__ float bf2f(u16 h) {
    u32 u = ((u32)h) << 16;
    return __builtin_bit_cast(float, u);
}

// m157-form bijective XCD swizzle (all grids have nwg % 8 == 0)
__device__ __forceinline__ void xcd_swizzle(int& bxs, int& bys) {
    const int GX  = gridDim.x;
    const int nwg = GX * gridDim.y;
    const int lid = blockIdx.y * GX + blockIdx.x;
    const int chunk = nwg >> 3;
    const int nlid  = (lid & 7) * chunk + (lid >> 3);
    bxs = nlid % GX;
    bys = nlid / GX;
}

// hi/lo bf16 split of a float4, written to two 8B LDS slots
__device__ __forceinline__ void split_write(char* hidst, char* lodst, float4 v) {
    u16 h0 = f2bf(v.x), h1 = f2bf(v.y), h2 = f2bf(v.z), h3 = f2bf(v.w);
    u16 l0 = f2bf(__fsub_rn(v.x, bf2f(h0)));
    u16 l1 = f2bf(__fsub_rn(v.y, bf2f(h1)));
    u16 l2 = f2bf(__fsub_rn(v.z, bf2f(h2)));
    u16 l3 = f2bf(__fsub_rn(v.w, bf2f(h3)));
    ushort4 hi; hi.x = h0; hi.y = h1; hi.z = h2; hi.w = h3;
    ushort4 lo; lo.x = l0; lo.y = l1; lo.z = l2; lo.w = l3;
    *(ushort4*)hidst = hi;
    *(ushort4*)lodst = lo;
}

// ---------------------------------------------------------------------------
// Split-2 bf16 MFMA GEMM, 128x128 tile, BK=32, 4 waves (2x2).
// SINGLE-buffer 32KB LDS, 2 barriers/K-step (m97 template).
// C = A@B^T(+bias), A = Ahi+Alo, B = Bhi+Blo; 3 MFMA per fragment pair.
// EPI=0 (H1): A = f32 (reg-stage + split), epilogue relu+bias -> hi/lo bf16.
// EPI=1 (DOTS+Z): A = bf16 pair. Col-tiles 0-3 (codes): full 3-MFMA split-2,
//   dist top-2 lex-min partials. Col-tiles 4-5 (z): 1 MFMA (hi*hi) only --
//   feeds znorm/loss which is lenient.
// ---------------------------------------------------------------------------
template<int EPI>
__global__ __launch_bounds__(256, 3)
void split2_gemm(const float* __restrict__ Af32,
                 const u16* __restrict__ Ahi, const u16* __restrict__ Alo,
                 const u16* __restrict__ Bhi, const u16* __restrict__ Blo,
                 const float* __restrict__ bias,
                 const float* __restrict__ cnorm,
                 u16* __restrict__ Chi, u16* __restrict__ Clo,
                 float* __restrict__ pd1, int* __restrict__ pi1,
                 float* __restrict__ pd2, float* __restrict__ pzn,
                 int M, int N, int K)
{
    __shared__ char lds[32768];   // A pair @0 (16K), B pair @16384 (16K)
    const int t = threadIdx.x, lane = t & 63, wid = t >> 6;
    const int wm = wid >> 1, wn = wid & 1;
    int bxs, bys; xcd_swizzle(bxs, bys);
    const int bm = bys * 128, bn = bxs * 128;
    const bool full3 = (EPI == 0) || (bxs < 4);

    // staging: 16 chunks of 1KB (8 rows x 128B); lane: row sr, slot sl (pre-swz)
    const int sr = lane >> 3, qq = lane & 7, sl = qq ^ sr;
    const u16* bsrc[4];
    #pragma unroll
    for (int c = 0; c < 4; c++) {
        int row = bn + (wid * 4 + c) * 8 + sr;
        const u16* base = (sl < 4) ? Bhi : Blo;
        bsrc[c] = base + (size_t)row * K + (sl & 3) * 8;
    }
    const u16* asrc[4];
    const float* a32src[4];
    int adhi[4], adlo[4];
    if constexpr (EPI == 1) {
        #pragma unroll
        for (int c = 0; c < 4; c++) {
            int row = bm + (wid * 4 + c) * 8 + sr;
            const u16* base = (sl < 4) ? Ahi : Alo;
            asrc[c] = base + (size_t)row * K + (sl & 3) * 8;
        }
    } else {
        #pragma unroll
        for (int c = 0; c < 4; c++) {
            int id = c * 256 + t;
            int row = id >> 3, k4 = id & 7;
            a32src[c] = Af32 + (size_t)(bm + row) * K + k4 * 4;
            int s = k4 >> 1, hf = k4 & 1;
            adhi[c] = row * 128 + ((s ^ (row & 7)) << 4) + hf * 8;
            adlo[c] = row * 128 + (((s | 4) ^ (row & 7)) << 4) + hf * 8;
        }
    }

    f32x4 acc[4][4];
    #pragma unroll
    for (int i = 0; i < 4; i++)
        #pragma unroll
        for (int j = 0; j < 4; j++) acc[i][j] = (f32x4)0.f;

    const int fr = lane & 15, sw = lane & 7;
    const int offhi = (((lane >> 4) ^ sw) << 4);
    const int offlo = ((((lane >> 4) | 4) ^ sw) << 4);
    const int arow = wm * 64 + fr, brow = wn * 64 + fr;
    const int NT = K >> 5;

    for (int tt = 0; tt < NT; tt++) {
        __syncthreads();              // previous tile's LDS reads done
        const int kadv = tt * 32;
        #pragma unroll
        for (int c = 0; c < 4; c++)
            gload16(bsrc[c] + kadv, lds + 16384 + (wid * 4 + c) * 1024);
        if constexpr (EPI == 1) {
            #pragma unroll
            for (int c = 0; c < 4; c++)
                gload16(asrc[c] + kadv, lds + (wid * 4 + c) * 1024);
        } else {
            #pragma unroll
            for (int c = 0; c < 4; c++) {
                float4 v = *(const float4*)(a32src[c] + kadv);
                split_write(lds + adhi[c], lds + adlo[c], v);
            }
        }
        __syncthreads();              // drains vmcnt/lgkm: tile staged
        char* ab  = lds;
        char* bb2 = lds + 16384;
        short8 ah[4], al[4];
        #pragma unroll
        for (int i = 0; i < 4; i++) {
            ah[i] = *(const short8*)(ab + ((arow + i * 16) << 7) + offhi);
            al[i] = *(const short8*)(ab + ((arow + i * 16) << 7) + offlo);
        }
        if (full3) {
            #pragma unroll
            for (int j = 0; j < 4; j++) {
                short8 bh = *(const short8*)(bb2 + ((brow + j * 16) << 7) + offhi);
                short8 bl = *(const short8*)(bb2 + ((brow + j * 16) << 7) + offlo);
                #pragma unroll
                for (int i = 0; i < 4; i++) {
                    acc[i][j] = __builtin_amdgcn_mfma_f32_16x16x32_bf16(ah[i], bh, acc[i][j], 0, 0, 0);
                    acc[i][j] = __builtin_amdgcn_mfma_f32_16x16x32_bf16(al[i], bh, acc[i][j], 0, 0, 0);
                    acc[i][j] = __builtin_amdgcn_mfma_f32_16x16x32_bf16(ah[i], bl, acc[i][j], 0, 0, 0);
                }
            }
        } else {
            #pragma unroll
            for (int j = 0; j < 4; j++) {
                short8 bh = *(const short8*)(bb2 + ((brow + j * 16) << 7) + offhi);
                #pragma unroll
                for (int i = 0; i < 4; i++)
                    acc[i][j] = __builtin_amdgcn_mfma_f32_16x16x32_bf16(ah[i], bh, acc[i][j], 0, 0, 0);
            }
        }
    }

    if constexpr (EPI == 1) {
        const int ec = lane & 15, g = lane >> 4;
        if (bxs < 4) {
            // code columns: dist top-2 partials
            float cnv[4], bcv[4];
            #pragma unroll
            for (int j = 0; j < 4; j++) {
                int c = bn + wn * 64 + j * 16 + ec;
                cnv[j] = cnorm[c]; bcv[j] = bias[c];
            }
            const int strip = bxs * 2 + wn;
            #pragma unroll
            for (int i = 0; i < 4; i++) {
                #pragma unroll
                for (int e = 0; e < 4; e++) {
                    float d1 = INFINITY, d2 = INFINITY; int i1 = 0x7fffffff;
                    #pragma unroll
                    for (int j = 0; j < 4; j++) {
                        int c = bn + wn * 64 + j * 16 + ec;
                        float d = __fsub_rn(cnv[j],
                                  __fmul_rn(2.0f, __fadd_rn(acc[i][j][e], bcv[j])));
                        if (d < d1 || (d == d1 && c < i1)) { d2 = d1; d1 = d; i1 = c; }
                        else if (d < d2) d2 = d;
                    }
                    #pragma unroll
                    for (int m = 1; m < 16; m <<= 1) {
                        float od1 = __shfl_xor(d1, m);
                        int   oi1 = __shfl_xor(i1, m);
                        float od2 = __shfl_xor(d2, m);
                        if (od1 < d1 || (od1 == d1 && oi1 < i1)) {
                            d2 = fminf(d1, od2); d1 = od1; i1 = oi1;
                        } else d2 = fminf(d2, od1);
                    }
                    if (ec == 0) {
                        int r = bm + wm * 64 + i * 16 + g * 4 + e;
                        pd1[(size_t)strip * M + r] = d1;
                        pi1[(size_t)strip * M + r] = i1;
                        pd2[(size_t)strip * M + r] = d2;
                    }
                }
            }
        } else {
            // z columns: znorm partials (z = acc + b2[col]; never stored)
            float bcv[4];
            #pragma unroll
            for (int j = 0; j < 4; j++)
                bcv[j] = bias[bn + wn * 64 + j * 16 + ec];
            const int zs = (bxs - 4) * 2 + wn;
            #pragma unroll
            for (int i = 0; i < 4; i++) {
                #pragma unroll
                for (int e = 0; e < 4; e++) {
                    float s = 0.f;
                    #pragma unroll
                    for (int j = 0; j < 4; j++) {
                        float zv = acc[i][j][e] + bcv[j];
                        s = fmaf(zv, zv, s);
                    }
                    #pragma unroll
                    for (int m = 1; m < 16; m <<= 1) s += __shfl_xor(s, m);
                    if (ec == 0) {
                        int r = bm + wm * 64 + i * 16 + g * 4 + e;
                        pzn[(size_t)zs * M + r] = s;
                    }
                }
            }
        }
        return;
    } else {
        const int er = (lane >> 4) * 4, ec = lane & 15;
        #pragma unroll
        for (int j = 0; j < 4; j++) {
            int col = bn + wn * 64 + j * 16 + ec;
            float bb = bias[col];
            #pragma unroll
            for (int i = 0; i < 4; i++) {
                #pragma unroll
                for (int e = 0; e < 4; e++) {
                    int r = bm + wm * 64 + i * 16 + er + e;
                    float v = fmaxf(__fadd_rn(acc[i][j][e], bb), 0.f);
                    u16 hi = f2bf(v);
                    u16 lo = f2bf(__fsub_rn(v, bf2f(hi)));
                    Chi[(size_t)r * N + col] = hi;
                    Clo[(size_t)r * N + col] = lo;
                }
            }
        }
    }
}

// ---------------------------------------------------------------------------
// Plain bf16 MFMA GEMM (tiny R-table GEMMs; lenient). Single-buffer 32KB,
// BK=64. C = act(A[M,K] @ BT[N,K]^T + bias).
// ---------------------------------------------------------------------------
template<bool RELU, bool OUT_BF16>
__global__ __launch_bounds__(256, 3)
void mfma_gemm(const u16* __restrict__ A, const u16* __restrict__ BT,
               const float* __restrict__ bias,
               void* __restrict__ Cout, int M, int N, int K)
{
    __shared__ char lds[32768];
    const int t    = threadIdx.x;
    const int lane = t & 63, wid = t >> 6;
    const int wm   = wid >> 1, wn = wid & 1;
    int bxs, bys;
    xcd_swizzle(bxs, bys);
    const int bm = bys * 128, bn = bxs * 128;

    const int sr = lane >> 3;
    const int sc = ((lane & 7) ^ sr) * 8;
    const u16* aptr[4];
    const u16* bptr[4];
    #pragma unroll
    for (int c = 0; c < 4; c++) {
        int gc   = wid * 4 + c;
        int arow = bm + 8 * gc + sr;
        aptr[c] = A  + (size_t)arow * K + sc;
        int brow = bn + 8 * gc + sr;
        bptr[c] = BT + (size_t)brow * K + sc;
    }

    f32x4 acc[4][4];
    #pragma unroll
    for (int i = 0; i < 4; i++)
        #pragma unroll
        for (int j = 0; j < 4; j++) acc[i][j] = (f32x4)0.f;

    const int koff0 = (16 * (lane >> 4))      ^ ((lane & 7) << 4);
    const int koff1 = (64 + 16 * (lane >> 4)) ^ ((lane & 7) << 4);
    const int arow_rd = wm * 64 + (lane & 15);
    const int brow_rd = wn * 64 + (lane & 15);

    const int NT = K >> 6;
    for (int tt = 0; tt < NT; tt++) {
        __syncthreads();
        const int k0 = tt << 6;
        #pragma unroll
        for (int c = 0; c < 4; c++) {
            int gc = wid * 4 + c;
            gload16(aptr[c] + k0, lds + gc * 1024);
            gload16(bptr[c] + k0, lds + 16384 + gc * 1024);
        }
        __syncthreads();
        char* ldsA = lds;
        char* ldsB = lds + 16384;
        #pragma unroll
        for (int kk = 0; kk < 2; kk++) {
            const int ko = kk ? koff1 : koff0;
            short8 af[4], bfr[4];
            #pragma unroll
            for (int i = 0; i < 4; i++)
                af[i]  = *(const short8*)(ldsA + (arow_rd + i * 16) * 128 + ko);
            #pragma unroll
            for (int j = 0; j < 4; j++)
                bfr[j] = *(const short8*)(ldsB + (brow_rd + j * 16) * 128 + ko);
            #pragma unroll
            for (int i = 0; i < 4; i++)
                #pragma unroll
                for (int j = 0; j < 4; j++)
                    acc[i][j] = __builtin_amdgcn_mfma_f32_16x16x32_bf16(
                        af[i], bfr[j], acc[i][j], 0, 0, 0);
        }
    }

    const int er = (lane >> 4) * 4;
    const int ec = lane & 15;
    #pragma unroll
    for (int j = 0; j < 4; j++) {
        int col  = bn + wn * 64 + j * 16 + ec;
        float bb = bias[col];
        #pragma unroll
        for (int i = 0; i < 4; i++) {
            #pragma unroll
            for (int e = 0; e < 4; e++) {
                int r   = bm + wm * 64 + i * 16 + er + e;
                float v = acc[i][j][e] + bb;
                if (RELU) v = fmaxf(v, 0.f);
                if (OUT_BF16) ((u16*)Cout)[(size_t)r * N + col]  = f2bf(v);
                else          ((float*)Cout)[(size_t)r * N + col] = v;
            }
        }
    }
}

// ---------------------------------------------------------------------------
// recon = R[idx[r]] broadcast-gather (R is 512x768 fp32, L2-resident).
// One wave per row: 64 lanes x 3 float4 = 768 floats. Memory-write bound.
// ---------------------------------------------------------------------------
__global__ __launch_bounds__(256)
void gather_out(const float* __restrict__ R, const int* __restrict__ idxi,
                float* __restrict__ out)
{
    int w    = (blockIdx.x * 256 + threadIdx.x) >> 6;
    int lane = threadIdx.x & 63;
    int nw   = (gridDim.x * 256) >> 6;
    for (int r = w; r < N_ROWS; r += nw) {
        int code = idxi[r];
        const float4* src = (const float4*)(R + (size_t)code * DIN);
        float4* dst = (float4*)(out + (size_t)r * DIN);
        dst[lane]       = src[lane];
        dst[lane + 64]  = src[lane + 64];
        dst[lane + 128] = src[lane + 128];
    }
}

// ---------------------------------------------------------------------------
// Prep kernels
// ---------------------------------------------------------------------------
__global__ void transpose_cb_kernel(const float* __restrict__ cb, float* __restrict__ cbT)
{
    int tid = blockIdx.x * 256 + threadIdx.x;   // 512*256
    int k = tid >> 8;
    int d = tid & 255;
    cbT[(size_t)d * KC + k] = cb[(size_t)k * DCODE + d];
}

__global__ void cast_bf16_kernel(const float* __restrict__ in, u16* __restrict__ out, int n)
{
    int i = blockIdx.x * 256 + threadIdx.x;
    if (i < n) out[i] = f2bf(in[i]);
}

// in [K][N] fp32 -> out [N][K] bf16
__global__ void castT_bf16_kernel(const float* __restrict__ in, u16* __restrict__ out,
                                  int K, int N)
{
    int i = blockIdx.x * 256 + threadIdx.x;
    if (i >= K * N) return;
    int n = i / K, k = i - n * K;
    out[i] = f2bf(in[(size_t)k * N + n]);
}

// W1 [768][512] -> W1T hi/lo [512][768]
__global__ void prep_W1T(const float* __restrict__ W1, u16* __restrict__ Thi,
                         u16* __restrict__ Tlo)
{
    int id = blockIdx.x * 256 + threadIdx.x;    // 512*768
    if (id >= DHID * DIN) return;
    int n = id / DIN, k = id - n * DIN;
    float v = W1[(size_t)k * DHID + n];
    u16 hi = f2bf(v);
    Thi[id] = hi;
    Tlo[id] = f2bf(__fsub_rn(v, bf2f(hi)));
}

// WfT rows 0-511: WcT[n][h] = sum_t W2[h][t]*cb[n][t] (fp64), split hi/lo
__global__ void prep_Wc(const float* __restrict__ W2, const float* __restrict__ cb,
                        u16* __restrict__ Thi, u16* __restrict__ Tlo)
{
    int id = blockIdx.x * 256 + threadIdx.x;    // 512*512
    int n = id & 511, h = id >> 9;
    double acc = 0.0;
    for (int tt2 = 0; tt2 < DCODE; tt2++)
        acc += (double)W2[(size_t)h * DCODE + tt2] * (double)cb[(size_t)n * DCODE + tt2];
    float v = (float)acc;
    u16 hi = f2bf(v);
    Thi[(size_t)n * DHID + h] = hi;
    Tlo[(size_t)n * DHID + h] = f2bf(__fsub_rn(v, bf2f(hi)));
}

// WfT rows 512-767: W2 [512][256] -> WfT[512+t2][h], split hi/lo
__global__ void prep_W2T_pair(const float* __restrict__ W2, u16* __restrict__ Thi,
                              u16* __restrict__ Tlo)
{
    int id = blockIdx.x * 256 + threadIdx.x;    // 256*512
    if (id >= DCODE * DHID) return;
    int t2 = id >> 9, h = id & 511;
    float v = W2[(size_t)h * DCODE + t2];
    u16 hi = f2bf(v);
    Thi[(size_t)(KC + t2) * DHID + h] = hi;
    Tlo[(size_t)(KC + t2) * DHID + h] = f2bf(__fsub_rn(v, bf2f(hi)));
}

// bcf[0..511] = fp64 b2·cb[n]; bcf[512..767] = b2[n-512]
__global__ void prep_bcf(const float* __restrict__ b2, const float* __restrict__ cb,
                         float* __restrict__ bcf)
{
    int n = blockIdx.x * 256 + threadIdx.x;
    if (n >= NFUSE) return;
    if (n < KC) {
        double acc = 0.0;
        for (int tt2 = 0; tt2 < DCODE; tt2++)
            acc += (double)b2[tt2] * (double)cb[(size_t)n * DCODE + tt2];
        bcf[n] = (float)acc;
    } else {
        bcf[n] = b2[n - KC];
    }
}

// ||c_k||^2 replicating numpy float32 pairwise-summation bitwise (ref-exact).
__global__ void cnorm_np_kernel(const float* __restrict__ cb, float* __restrict__ cnorm)
{
    int k = blockIdx.x * 64 + threadIdx.x;
    if (k >= KC) return;
    const float* c = cb + (size_t)k * DCODE;
    float bsum[2];
    #pragma unroll
    for (int b = 0; b < 2; b++) {
        const float* a = c + b * 128;
        float r[8];
        #pragma unroll
        for (int j = 0; j < 8; j++) r[j] = __fmul_rn(a[j], a[j]);
        for (int i = 8; i < 128; i += 8)
            #pragma unroll
            for (int j = 0; j < 8; j++)
                r[j] = __fadd_rn(r[j], __fmul_rn(a[i + j], a[i + j]));
        bsum[b] = __fadd_rn(
            __fadd_rn(__fadd_rn(r[0], r[1]), __fadd_rn(r[2], r[3])),
            __fadd_rn(__fadd_rn(r[4], r[5]), __fadd_rn(r[6], r[7])));
    }
    cnorm[k] = __fadd_rn(bsum[0], bsum[1]);
}

// ---------------------------------------------------------------------------
// Final merge of 8 strip top-2 partials + 4 znorm partials; flag gap < TAU.
// ---------------------------------------------------------------------------
__global__ void final_argmin_flag(const float* __restrict__ pd1,
                                  const int* __restrict__ pi1,
                                  const float* __restrict__ pd2,
                                  const float* __restrict__ pzn,
                                  float* __restrict__ idx_f,
                                  int* __restrict__ idx_i,
                                  float* __restrict__ rowloss,
                                  int* __restrict__ cnt,
                                  int* __restrict__ list)
{
    int r = blockIdx.x * 256 + threadIdx.x;
    if (r >= N_ROWS) return;
    float d1 = pd1[r]; int i1 = pi1[r]; float d2 = pd2[r];
    #pragma unroll
    for (int b = 1; b < 8; b++) {
        float od1 = pd1[(size_t)b * N_ROWS + r];
        int   oi1 = pi1[(size_t)b * N_ROWS + r];
        float od2 = pd2[(size_t)b * N_ROWS + r];
        if (od1 < d1 || (od1 == d1 && oi1 < i1)) {
            d2 = fminf(d1, od2); d1 = od1; i1 = oi1;
        } else d2 = fminf(d2, od1);
    }
    float zn = pzn[r] + pzn[(size_t)N_ROWS + r]
             + pzn[(size_t)2 * N_ROWS + r] + pzn[(size_t)3 * N_ROWS + r];
    idx_f[r]   = (float)i1;
    idx_i[r]   = i1;
    rowloss[r] = zn + d1;
    if (d2 - d1 < TAU) {
        int p = atomicAdd(cnt, 1);
        list[p] = r;
    }
}

// ---------------------------------------------------------------------------
// Bitwise fp32 recompute for contested rows (exact round-2 chain numerics).
// ---------------------------------------------------------------------------
__global__ __launch_bounds__(512)
void recompute_kernel(const float* __restrict__ x,  const float* __restrict__ W1,
                      const float* __restrict__ b1, const float* __restrict__ W2,
                      const float* __restrict__ b2, const float* __restrict__ cbT,
                      const float* __restrict__ cnorm,
                      const int* __restrict__ cnt,  const int* __restrict__ list,
                      float* __restrict__ idx_f,    int* __restrict__ idx_i)
{
    __shared__ float xs[8][DIN];
    __shared__ float h1s[8][DHID];
    __shared__ float zs[8][DCODE];
    __shared__ float swd[8][8];
    __shared__ int   swi[8][8];
    __shared__ int   rls[8];
    const int t = threadIdx.x;
    const int n = *cnt;

    for (int base = blockIdx.x * 8; base < n; base += gridDim.x * 8) {
        __syncthreads();
        if (t < 8) rls[t] = (base + t < n) ? list[base + t] : -1;
        __syncthreads();
        #pragma unroll
        for (int rr = 0; rr < 8; rr++) {
            int row = rls[rr];
            if (row >= 0)
                for (int i = t; i < DIN; i += 512)
                    xs[rr][i] = x[(size_t)row * DIN + i];
        }
        __syncthreads();
        {
            float acc[8] = {0.f,0.f,0.f,0.f,0.f,0.f,0.f,0.f};
            for (int i = 0; i < DIN; i++) {
                float w = W1[(size_t)i * DHID + t];
                #pragma unroll
                for (int rr = 0; rr < 8; rr++)
                    acc[rr] = fmaf(xs[rr][i], w, acc[rr]);
            }
            float bb = b1[t];
            #pragma unroll
            for (int rr = 0; rr < 8; rr++)
                h1s[rr][t] = fmaxf(__fadd_rn(acc[rr], bb), 0.f);
        }
        __syncthreads();
        {
            int half = t >> 8, t2 = t & 255;
            float acc[4] = {0.f,0.f,0.f,0.f};
            for (int h = 0; h < DHID; h++) {
                float w = W2[(size_t)h * DCODE + t2];
                #pragma unroll
                for (int q2 = 0; q2 < 4; q2++)
                    acc[q2] = fmaf(h1s[half * 4 + q2][h], w, acc[q2]);
            }
            float bb = b2[t2];
            #pragma unroll
            for (int q2 = 0; q2 < 4; q2++)
                zs[half * 4 + q2][t2] = __fadd_rn(acc[q2], bb);
        }
        __syncthreads();
        {
            float acc[8] = {0.f,0.f,0.f,0.f,0.f,0.f,0.f,0.f};
            for (int d = 0; d < DCODE; d++) {
                float c = cbT[(size_t)d * KC + t];
                #pragma unroll
                for (int rr = 0; rr < 8; rr++)
                    acc[rr] = fmaf(zs[rr][d], c, acc[rr]);
            }
            float cn = cnorm[t];
            #pragma unroll
            for (int rr = 0; rr < 8; rr++) {
                float d = __fsub_rn(cn, __fmul_rn(2.0f, acc[rr]));
                int ii = t;
                #pragma unroll
                for (int m = 1; m < 64; m <<= 1) {
                    float od = __shfl_xor(d, m);
                    int   oi = __shfl_xor(ii, m);
                    if (od < d || (od == d && oi < ii)) { d = od; ii = oi; }
                }
                if ((t & 63) == 0) { swd[rr][t >> 6] = d; swi[rr][t >> 6] = ii; }
            }
        }
        __syncthreads();
        if (t < 8) {
            int row = rls[t];
            if (row >= 0) {
                float d = swd[t][0]; int ii = swi[t][0];
                #pragma unroll
                for (int w = 1; w < 8; w++) {
                    float od = swd[t][w]; int oi = swi[t][w];
                    if (od < d || (od == d && oi < ii)) { d = od; ii = oi; }
                }
                idx_i[row] = ii;
                idx_f[row] = (float)ii;
            }
        }
    }
}

// ---------------------------------------------------------------------------
__global__ void loss_reduce_kernel(const float* __restrict__ rowloss,
                                   double* __restrict__ acc, int n)
{
    double s = 0.0;
    for (int i = blockIdx.x * blockDim.x + threadIdx.x; i < n; i += gridDim.x * blockDim.x)
        s += (double)rowloss[i];
    for (int off = 32; off; off >>= 1) s += __shfl_xor(s, off);
    __shared__ double red[4];
    int lane = threadIdx.x & 63, wave = threadIdx.x >> 6;
    if (lane == 0) red[wave] = s;
    __syncthreads();
    if (threadIdx.x == 0) {
        double b = red[0] + red[1] + red[2] + red[3];
        atomicAdd(acc, b);
    }
}

__global__ void finalize_kernel(const double* __restrict__ acc, float* __restrict__ out)
{
    out[0] = (float)(acc[0] / ((double)N_ROWS * (double)DCODE));
}

// ---------------------------------------------------------------------------
extern "C" void kernel_launch(void* const* d_in, const int* in_sizes, int n_in,
                              void* d_out, int out_size, void* d_ws, size_t ws_size,
                              hipStream_t stream)
{
    const float* x  = (const float*)d_in[0];
    const float* W1 = (const float*)d_in[1];
    const float* b1 = (const float*)d_in[2];
    const float* W2 = (const float*)d_in[3];
    const float* b2 = (const float*)d_in[4];
    const float* cb = (const float*)d_in[5];
    const float* W3 = (const float*)d_in[6];
    const float* b3 = (const float*)d_in[7];
    const float* W4 = (const float*)d_in[8];
    const float* b4 = (const float*)d_in[9];
    float* out = (float*)d_out;
    char*  ws  = (char*)d_ws;

    u16*    h1hi    = (u16*)   (ws);                      // 134217728
    u16*    h1lo    = (u16*)   (ws + 134217728);          // 134217728
    float*  pd1     = (float*) (ws + 268435456);          // 4194304
    int*    pi1     = (int*)   (ws + 272629760);          // 4194304
    float*  pd2     = (float*) (ws + 276824064);          // 4194304
    float*  pzn     = (float*) (ws + 281018368);          // 2097152
    float*  rowloss = (float*) (ws + 283115520);          // 524288
    int*    idxi    = (int*)   (ws + 283639808);          // 524288
    int*    list    = (int*)   (ws + 284164096);          // 524288
    int*    rcnt    = (int*)   (ws + 284688384);          // 64
    double* lossa   = (double*)(ws + 284688448);          // 64
    u16*    W1Thi   = (u16*)   (ws + 284688512);          // 786432
    u16*    W1Tlo   = (u16*)   (ws + 285474944);          // 786432
    u16*    WfThi   = (u16*)   (ws + 286261376);          // 786432 (768x512)
    u16*    WfTlo   = (u16*)   (ws + 287047808);          // 786432
    u16*    cbB     = (u16*)   (ws + 287834240);          // 262144
    u16*    W3T     = (u16*)   (ws + 288096384);          // 262144
    u16*    W4T     = (u16*)   (ws + 288358528);          // 786432
    float*  bcf     = (float*) (ws + 289144960);          // 3072
    float*  cnorm   = (float*) (ws + 289148032);          // 2048
    float*  cbT     = (float*) (ws + 289150080);          // 524288
    u16*    R1b     = (u16*)   (ws + 289674368);          // 524288 (512x512 bf16)
    float*  Rf      = (float*) (ws + 290198656);          // 1572864 (512x768 f32)

    float* idxf    = out + (size_t)N_ROWS * DIN;
    float* lossout = idxf + N_ROWS;

    hipMemsetAsync(ws + 284688384, 0, 128, stream);       // rcnt + lossa

    // prep
    transpose_cb_kernel<<<512, 256, 0, stream>>>(cb, cbT);
    cnorm_np_kernel<<<8, 64, 0, stream>>>(cb, cnorm);
    cast_bf16_kernel<<<(KC*DCODE)/256, 256, 0, stream>>>(cb, cbB, KC*DCODE);
    castT_bf16_kernel<<<(DCODE*DHID)/256, 256, 0, stream>>>(W3, W3T, DCODE, DHID);
    castT_bf16_kernel<<<(DHID*DIN)/256, 256, 0, stream>>>(W4, W4T, DHID, DIN);
    prep_W1T<<<(DHID*DIN)/256, 256, 0, stream>>>(W1, W1Thi, W1Tlo);
    prep_Wc<<<(KC*DHID)/256, 256, 0, stream>>>(W2, cb, WfThi, WfTlo);
    prep_W2T_pair<<<(DCODE*DHID)/256, 256, 0, stream>>>(W2, WfThi, WfTlo);
    prep_bcf<<<3, 256, 0, stream>>>(b2, cb, bcf);

    // decoder table R[512][768] = relu(cb@W3+b3)@W4+b4 (two tiny MFMA GEMMs)
    mfma_gemm<true,  true ><<<dim3(4, 4), 256, 0, stream>>>(
        cbB, W3T, b3, (void*)R1b, KC, DHID, DCODE);
    mfma_gemm<false, false><<<dim3(6, 4), 256, 0, stream>>>(
        R1b, W4T, b4, (void*)Rf, KC, DIN, DHID);

    // fast index path: split-2 bf16 MFMA
    split2_gemm<0><<<dim3(DHID/128, N_ROWS/128), 256, 0, stream>>>(
        x, nullptr, nullptr, W1Thi, W1Tlo, b1, nullptr,
        h1hi, h1lo, nullptr, nullptr, nullptr, nullptr, N_ROWS, DHID, DIN);
    // dots (cols 0-511, split-2) + znorm (cols 512-767, hi*hi) fused
    split2_gemm<1><<<dim3(NFUSE/128, N_ROWS/128), 256, 0, stream>>>(
        nullptr, h1hi, h1lo, WfThi, WfTlo, bcf, cnorm,
        nullptr, nullptr, pd1, pi1, pd2, pzn, N_ROWS, NFUSE, DHID);

    // merge + flag + bitwise recompute of contested rows
    final_argmin_flag<<<N_ROWS/256, 256, 0, stream>>>(
        pd1, pi1, pd2, pzn, idxf, idxi, rowloss, rcnt, list);
    recompute_kernel<<<2048, 512, 0, stream>>>(
        x, W1, b1, W2, b2, cbT, cnorm, rcnt, list, idxf, idxi);

    // recon = R[idx] broadcast-gather (memory-write bound)
    gather_out<<<4096, 256, 0, stream>>>(Rf, idxi, out);

    loss_reduce_kernel<<<256, 256, 0, stream>>>(rowloss, lossa, N_ROWS);
    finalize_kernel<<<1, 1, 0, stream>>>(lossa, lossout);
}